// Round 8
// baseline (339.377 us; speedup 1.0000x reference)
//
#include <hip/hip_runtime.h>
#include <math.h>

typedef _Float16 f16x8 __attribute__((ext_vector_type(8)));
typedef float f32x4 __attribute__((ext_vector_type(4)));

#define CIN 8
#define HIN 128
#define WIN 128
#define OH 126
#define OW 126
#define COUT 64
#define NB 128
#define NGROUPS 16
#define CPG 4
#define PWN 31
#define XROWS 34
#define XH_DIM 130            // padded image (2 halo rows/cols of zeros)
#define TPIX (34*34)          // 1156 pixels per tile
#define XSPAD 3072            // pads LDS to ~55KB -> 2 blocks/CU (proven R5 geometry)

// ---- ws layout (bytes) ----
// xh f16 [b][iy][ix][ci] | wext f16 [b][wy][wx][c] | parts f32 | ctr i32[NB]
#define XH_BYTES   ((size_t)NB*XH_DIM*XH_DIM*CIN*2)          // 34,611,200
#define WEXT_BYTES ((size_t)NB*PWN*PWN*COUT*2)               // 15,745,024
#define PART_BYTES ((size_t)NB*NGROUPS*4*2*4)                //     65,536
#define CTR_BYTES  ((size_t)NB*4)                            //        512
#define WS_NEEDED  (XH_BYTES + WEXT_BYTES + PART_BYTES + CTR_BYTES)

// ---- old (fallback) ws layout ----
#define NPOOL (NB*PWN*PWN*COUT)
#define OFF_PART_OLD (NPOOL/2)   // f32 offset

// ============================================================
// R8: tail kernel DELETED — folded into conv via last-block-done.
// Accounting across R0-R7: total - conv = 75..97us with the same tail
// kernel (xpack itself only ~15-25us). The 2048-tiny-block tail +
// launch overhead is the dominant remaining cost, bigger than conv.
// Each batch has exactly 4 conv blocks; after stats, each does
// threadfence + agent-scope atomic_fetch_add(ctr[b]); the one seeing
// prev==3 (acquire) owns the batch tail: AB from the 4 partials, then
// gather-affine-clamp-transpose (123KB wext read, L3-hot after the
// release fences; 246KB coalesced out write; no barriers, 120-deep
// ILP). No spinning -> no dispatch-order assumption (G16-safe).
// R7 lesson honored: conv compute loop is byte-identical to R5's
// measured-62us structure (pack stays a separate kernel; its scalar
// loads must NOT share the vmcnt-drained loop).
// ============================================================

// Pre-pack: x f32 NCHW -> xh f16 [b][iy][ix][ci] with zero halo.
// Extra gridDim.x slot zeroes the per-batch tail counters.
__global__ __launch_bounds__(192)
void xpack_kernel(const float* __restrict__ x, _Float16* __restrict__ xh,
                  int* __restrict__ ctr)
{
  const int iy = blockIdx.x;      // 0..129; 130 -> zero ctr[b]
  const int b  = blockIdx.y;
  if (iy == XH_DIM) {
    if (threadIdx.x == 0) ctr[b] = 0;
    return;
  }
  const int ix = threadIdx.x;     // active < 130
  if (ix >= XH_DIM) return;
  f16x8 pk = {0,0,0,0,0,0,0,0};
  if (iy < HIN && ix < WIN) {
    const float* xb = x + (size_t)b*CIN*HIN*WIN + iy*WIN + ix;
    #pragma unroll
    for (int ci = 0; ci < 8; ++ci)
      pk[ci] = (_Float16)xb[ci*HIN*WIN];
  }
  *(f16x8*)&xh[(((size_t)b*XH_DIM + iy)*XH_DIM + ix)*CIN] = pk;
}

__global__ __launch_bounds__(512)
void conv_tail_kernel(const _Float16* __restrict__ xh,
                      const float* __restrict__ w,
                      const float* __restrict__ bias,
                      const float* __restrict__ gnw,
                      const float* __restrict__ gnb,
                      const float* __restrict__ scale,
                      _Float16* __restrict__ wext,
                      float* __restrict__ parts,
                      int* __restrict__ ctr,
                      float* __restrict__ out)
{
  __shared__ __align__(16) _Float16 xs[2][TPIX*8 + XSPAD]; // 2 x 24,640 B
  __shared__ __align__(8)  _Float16 sbuf[8][256];          //   4,096 B
  __shared__ float red[8][16][2];                          //   1,024 B
  __shared__ float AB[128];
  __shared__ float stat[NGROUPS*2];
  __shared__ int   lastflag;

  const int tid  = threadIdx.x;
  const int lane = tid & 63, wv = tid >> 6;     // 8 waves
  const int tx = blockIdx.x;                    // 0..3 (tile column)
  const int b  = blockIdx.y;
  const int ox0 = tx*32;
  const int q = lane >> 4, ln = lane & 15;

  // DMA one tile into xs[buf]: one f16x8 pixel per lane per instr.
  auto stage = [&](int buf, int ty) {
    const int oy0 = ty*32;
    #pragma unroll
    for (int k = 0; k < 3; ++k) {
      const int p = k*512 + tid;
      if (p < TPIX) {
        const int r = p / 34, c = p - r*34;
        const size_t gb = (((size_t)b*XH_DIM + (oy0 + r))*XH_DIM + (ox0 + c))*CIN;
        __builtin_amdgcn_global_load_lds(
            (const __attribute__((address_space(1))) void*)(xh + gb),
            (__attribute__((address_space(3))) void*)&xs[buf][p*8],
            16, 0, 0);
      }
    }
  };

  stage(0, 0);

  // B fragments straight from global w (L2-hot, once per block).
  f16x8 bf[4][3];
  #pragma unroll
  for (int nt = 0; nt < 4; ++nt) {
    const int n = nt*16 + ln;
    #pragma unroll
    for (int c = 0; c < 2; ++c) {
      const int khw = c*4 + q;
      #pragma unroll
      for (int ci = 0; ci < 8; ++ci)
        bf[nt][c][ci] = (_Float16)w[(n*CIN + ci)*9 + khw];
    }
    if (q == 0) {
      #pragma unroll
      for (int ci = 0; ci < 8; ++ci)
        bf[nt][2][ci] = (_Float16)w[(n*CIN + ci)*9 + 8];
    } else {
      bf[nt][2] = (f16x8){0,0,0,0,0,0,0,0};
    }
  }

  // strip A offsets: lane ln = x-offset m, quad q picks khw = c*4+q.
  int aoff[3];
  #pragma unroll
  for (int c = 0; c < 3; ++c) {
    const int khw = c*4 + q;               // 0..11
    const int ky = khw / 3, kx = khw - 3*(khw/3);
    aoff[c] = (khw < 9) ? (ky*34 + kx + ln)*8 : ln*8;  // padded taps -> B=0
  }

  float bias_r[4], sgn[4];
  #pragma unroll
  for (int nt = 0; nt < 4; ++nt) {
    const int c = nt*16 + ln;
    bias_r[nt] = bias[c];
    sgn[nt] = (gnw[c]*scale[c] >= 0.f) ? 1.f : -1.f;  // GN slope sign (inv>0)
  }

  float s[4]  = {0.f,0.f,0.f,0.f};
  float sq[4] = {0.f,0.f,0.f,0.f};

  // stats x-mask: strip positions 14,15 (q==3, regs 2,3) are conv-x
  // 126,127 when tx==3 && bd==1 -> excluded.
  const float xm_hi = (q < 3) ? 1.f : 0.f;

  asm volatile("s_waitcnt vmcnt(0)" ::: "memory");
  __syncthreads();

  for (int ty = 0; ty < 4; ++ty) {
    const int cur = ty & 1;
    if (ty < 3) stage(cur ^ 1, ty + 1);    // async prefetch next tile

    const int wy_g = ty*8 + wv;
    const int oy0  = ty*32;

    // 2 bands per wave (x0 = 0, 16); band = 4 strips = 4 pool windows
    #pragma unroll
    for (int bd = 0; bd < 2; ++bd) {
      const int x0 = bd << 4;
      const bool xedge = (tx == 3) && (bd == 1);

      float mx[4] = {-1e30f, -1e30f, -1e30f, -1e30f};

      #pragma unroll
      for (int sy = 0; sy < 4; ++sy) {
        const int y_l = wv*4 + sy;
        if (oy0 + y_l >= OH) break;        // uniform: only ty==3, wv==7, sy>=2
        const int base = (y_l*34 + x0)*8;

        f32x4 acc[4];
        #pragma unroll
        for (int nt = 0; nt < 4; ++nt) {
          const float bv = bias_r[nt];
          acc[nt] = (f32x4){bv, bv, bv, bv};  // bias as MFMA C operand
        }
        #pragma unroll
        for (int c = 0; c < 3; ++c) {
          const f16x8 a = *(const f16x8*)&xs[cur][base + aoff[c]];
          #pragma unroll
          for (int nt = 0; nt < 4; ++nt)
            acc[nt] = __builtin_amdgcn_mfma_f32_16x16x32_f16(a, bf[nt][c], acc[nt], 0, 0, 0);
        }

        // fully in-lane: stats + running window max (sign-domain)
        #pragma unroll
        for (int nt = 0; nt < 4; ++nt) {
          float v0 = acc[nt][0], v1 = acc[nt][1];
          float v2 = acc[nt][2], v3 = acc[nt][3];
          if (xedge) { v2 *= xm_hi; v3 *= xm_hi; }   // mask conv-x 126,127
          s[nt]  += (v0+v1) + (v2+v3);
          sq[nt] += v0*v0 + v1*v1 + v2*v2 + v3*v3;
          const float sg = sgn[nt];
          const float m = fmaxf(fmaxf(sg*v0, sg*v1), fmaxf(sg*v2, sg*v3));
          mx[nt] = fmaxf(mx[nt], m);
        }
      }

      // store band's 4 pooled windows: sbuf bounce -> coalesced store
      if (wy_g < PWN) {
        #pragma unroll
        for (int nt = 0; nt < 4; ++nt)
          sbuf[wv][q*64 + nt*16 + ln] = (_Float16)(sgn[nt]*mx[nt]);
        const int nw = xedge ? 3 : 4;      // window wx_g==31 dropped
        if (lane < nw*16) {
          const int wx0_g = tx*8 + (x0 >> 2);
          const uint2 v = *(const uint2*)&sbuf[wv][lane*4];
          *(uint2*)&wext[(((size_t)b*PWN + wy_g)*PWN + wx0_g)*COUT + lane*4] = v;
        }
      }
    }

    if (ty < 3) {
      asm volatile("s_waitcnt vmcnt(0)" ::: "memory");  // next-tile DMA done
      __syncthreads();                                   // visible to all waves
    }
  }

  // per-wave stat reduce: quads (xor 16,32) then channels-in-group (xor 1,2)
  #pragma unroll
  for (int nt = 0; nt < 4; ++nt) {
    float a = s[nt], c2 = sq[nt];
    a  += __shfl_xor(a, 16, 64);  a  += __shfl_xor(a, 32, 64);
    a  += __shfl_xor(a, 1, 64);   a  += __shfl_xor(a, 2, 64);
    c2 += __shfl_xor(c2, 16, 64); c2 += __shfl_xor(c2, 32, 64);
    c2 += __shfl_xor(c2, 1, 64);  c2 += __shfl_xor(c2, 2, 64);
    if (lane < 16 && (lane & 3) == 0) {
      red[wv][nt*4 + (ln >> 2)][0] = a;
      red[wv][nt*4 + (ln >> 2)][1] = c2;
    }
  }
  __syncthreads();
  if (tid < 32) {
    const int g = tid >> 1, k = tid & 1;
    float t = 0.f;
    #pragma unroll
    for (int w8 = 0; w8 < 8; ++w8) t += red[w8][g][k];
    parts[(((size_t)b*NGROUPS + g)*4 + tx)*2 + k] = t;
  }

  // ---- last-block-done: the 4th finisher of batch b runs the tail ----
  __threadfence();               // release: wext + parts device-visible
  __syncthreads();               // all threads' fences done before the RMW
  if (tid == 0) {
    const int prev = __hip_atomic_fetch_add(&ctr[b], 1,
                        __ATOMIC_ACQ_REL, __HIP_MEMORY_SCOPE_AGENT);
    lastflag = (prev == 3);
  }
  __syncthreads();
  if (!lastflag) return;

  // stats for the whole batch (4 column partials per group)
  if (tid < 32) {
    const int g = tid >> 1, k = tid & 1;
    const float* p = parts + ((size_t)(b*NGROUPS + g)*4)*2 + k;
    stat[g*2 + k] = p[0] + p[2] + p[4] + p[6];
  }
  __syncthreads();
  if (tid < COUT) {
    const int c = tid, g = c >> 2;
    const float N = (float)(CPG * OH * OW);
    const float mean = stat[g*2] / N;
    const float var  = stat[g*2 + 1] / N - mean*mean;
    const float inv  = rsqrtf(var + 1e-5f);
    const float ag   = inv * gnw[c];
    AB[c]      = ag * scale[c];
    AB[64 + c] = (gnb[c] - mean * ag) * scale[c];
  }
  __syncthreads();

  // affine+clamp+NCHW-transpose for the whole batch.
  // Reads: stride-128B gathers, L2/L3-hot (123KB); writes: coalesced.
  const _Float16* wb = wext + (size_t)b*PWN*PWN*COUT;
  float* ob = out + (size_t)b*COUT*PWN*PWN;
  for (int o = tid; o < COUT*PWN*PWN; o += 512) {
    const int c = o / (PWN*PWN);           // magic-mul
    const int rem = o - c*(PWN*PWN);       // wy*31+wx
    const float v = fmaf(AB[c], (float)wb[rem*COUT + c], AB[64 + c]);
    ob[o] = fminf(fmaxf(v, 0.f), 1.f);
  }
}

// ============================================================
// Fallback conv (proven R0/R2 path, old ws layout; keeps bias).
// ============================================================
__global__ __launch_bounds__(256)
void conv_mfma_kernel(const float* __restrict__ x,
                      const float* __restrict__ w,
                      const float* __restrict__ bias,
                      const float* __restrict__ gnw,
                      const float* __restrict__ scale,
                      float* __restrict__ ws)
{
  __shared__ __align__(16) _Float16 xs[XROWS*34*8];
  __shared__ __align__(16) _Float16 wls[9*64*8];
  __shared__ float red[4][16][2];

  const int tid  = threadIdx.x;
  const int lane = tid & 63, wave = tid >> 6;
  const int tileIdx = blockIdx.x;
  const int tx = tileIdx & 3, ty = tileIdx >> 2;
  const int b  = blockIdx.y;
  const int ox0 = tx*32, oy0 = ty*32;

  for (int idx = tid; idx < 9*64*8; idx += 256) {
    const int ci = idx & 7, n = (idx >> 3) & 63, khw = idx >> 9;
    wls[idx] = (_Float16)w[(n*CIN + ci)*9 + khw];
  }
  const float* xb = x + (size_t)b * CIN*HIN*WIN;
  for (int p = tid; p < XROWS*34; p += 256) {
    const int r = p / 34, c = p - r*34;
    const int iy = oy0 + r, ix = ox0 + c;
    const bool ok = (iy < HIN) && (ix < WIN);
    const int gbase = iy*WIN + ix;
    f16x8 pk;
    #pragma unroll
    for (int ci = 0; ci < 8; ++ci) {
      const float v = ok ? xb[ci*HIN*WIN + gbase] : 0.f;
      pk[ci] = (_Float16)v;
    }
    *(f16x8*)&xs[p*8] = pk;
  }
  __syncthreads();

  const int q = lane >> 4, ln = lane & 15;
  f16x8 bf[4][3];
  #pragma unroll
  for (int nt = 0; nt < 4; ++nt) {
    #pragma unroll
    for (int c = 0; c < 2; ++c)
      bf[nt][c] = *(const f16x8*)&wls[((c*4 + q)*64 + nt*16 + ln)*8];
    if (q == 0) bf[nt][2] = *(const f16x8*)&wls[((8)*64 + nt*16 + ln)*8];
    else        bf[nt][2] = (f16x8){0,0,0,0,0,0,0,0};
  }
  const int dy = ln >> 2, dx = ln & 3;
  int aoff[3];
  #pragma unroll
  for (int c = 0; c < 3; ++c) {
    const int khw = c*4 + q;
    const int ky = khw / 3, kx = khw - 3*(khw/3);
    aoff[c] = (khw < 9) ? ((dy + ky)*34 + (dx + kx))*8 : 0;
  }
  float bias_r[4], sgn[4];
  #pragma unroll
  for (int nt = 0; nt < 4; ++nt) {
    const int c = nt*16 + ln;
    bias_r[nt] = bias[c];
    sgn[nt] = (gnw[c]*scale[c] >= 0.f) ? 1.f : -1.f;
  }
  float s[4]  = {0.f,0.f,0.f,0.f};
  float sq[4] = {0.f,0.f,0.f,0.f};
  _Float16* wext = (_Float16*)ws;

  #pragma unroll 2
  for (int i = 0; i < 16; ++i) {
    const int wyl = wave*2 + (i >> 3), wxl = i & 7;
    const int base = (wyl*4*34 + wxl*4)*8;
    f32x4 acc[4];
    #pragma unroll
    for (int nt = 0; nt < 4; ++nt) {
      const float bv = bias_r[nt];
      acc[nt] = (f32x4){bv, bv, bv, bv};
    }
    #pragma unroll
    for (int c = 0; c < 3; ++c) {
      const f16x8 a = *(const f16x8*)&xs[base + aoff[c]];
      #pragma unroll
      for (int nt = 0; nt < 4; ++nt)
        acc[nt] = __builtin_amdgcn_mfma_f32_16x16x32_f16(a, bf[nt][c], acc[nt], 0, 0, 0);
    }
    const int wyg = ty*8 + wyl, wxg = tx*8 + wxl;
    if ((wyg < PWN) && (wxg < PWN)) {
      const size_t rowbase = ((size_t)(b*PWN + wyg)*PWN + wxg)*COUT;
      float m4[4];
      #pragma unroll
      for (int nt = 0; nt < 4; ++nt) {
        const float v0 = acc[nt][0], v1 = acc[nt][1];
        const float v2 = acc[nt][2], v3 = acc[nt][3];
        s[nt]  += (v0+v1) + (v2+v3);
        sq[nt] += v0*v0 + v1*v1 + v2*v2 + v3*v3;
        const float sg = sgn[nt];
        float m = fmaxf(fmaxf(sg*v0, sg*v1), fmaxf(sg*v2, sg*v3));
        m = fmaxf(m, __shfl_xor(m, 16, 64));
        m = fmaxf(m, __shfl_xor(m, 32, 64));
        m4[nt] = sg*m;
      }
      float mv = m4[0];
      mv = (q == 1) ? m4[1] : mv;
      mv = (q == 2) ? m4[2] : mv;
      mv = (q == 3) ? m4[3] : mv;
      wext[rowbase + lane] = (_Float16)mv;
    } else {
      const bool yv = (wyg*4 + q) < OH;
      #pragma unroll
      for (int nt = 0; nt < 4; ++nt) {
        #pragma unroll
        for (int r = 0; r < 4; ++r) {
          const bool okp = yv && (wxg*4 + r < OW);
          const float v = okp ? acc[nt][r] : 0.f;
          s[nt] += v; sq[nt] += v*v;
        }
      }
    }
  }
  #pragma unroll
  for (int nt = 0; nt < 4; ++nt) {
    float a = s[nt], c2 = sq[nt];
    a  += __shfl_xor(a, 16, 64);  a  += __shfl_xor(a, 32, 64);
    a  += __shfl_xor(a, 1, 64);   a  += __shfl_xor(a, 2, 64);
    c2 += __shfl_xor(c2, 16, 64); c2 += __shfl_xor(c2, 32, 64);
    c2 += __shfl_xor(c2, 1, 64);  c2 += __shfl_xor(c2, 2, 64);
    if (lane < 16 && (lane & 3) == 0) {
      red[wave][nt*4 + (ln >> 2)][0] = a;
      red[wave][nt*4 + (ln >> 2)][1] = c2;
    }
  }
  __syncthreads();
  if (tid < 32) {
    const int g = tid >> 1, k = tid & 1;
    const float t = red[0][g][k] + red[1][g][k] + red[2][g][k] + red[3][g][k];
    ws[OFF_PART_OLD + (((size_t)b*NGROUPS + g)*16 + tileIdx)*2 + k] = t;
  }
}

// ============================================================
// Fallback tail (old ws layout only).
// ============================================================
__global__ __launch_bounds__(256)
void tail_kernel(const float* __restrict__ gnw,
                 const float* __restrict__ gnb,
                 const float* __restrict__ scale,
                 const _Float16* __restrict__ wext,
                 const float* __restrict__ parts,
                 const int nparts,
                 float* __restrict__ out)
{
  __shared__ float stat[NGROUPS*2];
  __shared__ float AB[128];
  __shared__ float vout[COUT*PWN];

  const int tid = threadIdx.x;
  const int xb  = blockIdx.x;
  const int b   = blockIdx.y;

  if (tid < 32) {
    const int g = tid >> 1, k = tid & 1;
    const float* p = parts + ((size_t)(b*NGROUPS + g)*nparts)*2 + k;
    float a = 0.f;
    for (int t = 0; t < nparts; ++t) a += p[t*2];
    stat[g*2 + k] = a;
  }
  __syncthreads();
  if (tid < COUT) {
    const int c = tid, g = c >> 2;
    const float N = (float)(CPG * OH * OW);
    const float mean = stat[g*2] / N;
    const float var  = stat[g*2 + 1] / N - mean*mean;
    const float inv  = rsqrtf(var + 1e-5f);
    const float ag   = inv * gnw[c];
    AB[c]      = ag * scale[c];
    AB[64 + c] = (gnb[c] - mean * ag) * scale[c];
  }
  __syncthreads();

  #pragma unroll
  for (int r = 0; r < 2; ++r) {
    const int wy = xb*2 + r;
    if (wy >= PWN) break;
    const size_t rb = (size_t)(b*PWN + wy)*PWN*COUT;

    if (tid < 248) {
      const f16x8 e = *(const f16x8*)&wext[rb + tid*8];
      const int wx = tid >> 3, c0 = (tid & 7)*8;
      #pragma unroll
      for (int j = 0; j < 8; ++j) {
        const int c = c0 + j;
        float v = fmaf(AB[c], (float)e[j], AB[64 + c]);
        v = fminf(fmaxf(v, 0.f), 1.f);
        vout[c*PWN + wx] = v;
      }
    }
    __syncthreads();
    for (int e = tid; e < COUT*PWN; e += 256) {
      const int c = e / PWN, wx = e - c*PWN;
      out[(((size_t)b*COUT + c)*PWN + wy)*PWN + wx] = vout[e];
    }
    __syncthreads();
  }
}

extern "C" void kernel_launch(void* const* d_in, const int* in_sizes, int n_in,
                              void* d_out, int out_size, void* d_ws, size_t ws_size,
                              hipStream_t stream)
{
  const float* x     = (const float*)d_in[0];
  const float* cw    = (const float*)d_in[1];
  const float* cb    = (const float*)d_in[2];
  const float* gnw   = (const float*)d_in[3];
  const float* gnb   = (const float*)d_in[4];
  const float* scale = (const float*)d_in[5];
  float* out = (float*)d_out;
  float* ws  = (float*)d_ws;

  if (ws_size >= WS_NEEDED) {
    _Float16* xh   = (_Float16*)ws;
    _Float16* wext = (_Float16*)((char*)ws + XH_BYTES);
    float*    prt  = (float*)((char*)ws + XH_BYTES + WEXT_BYTES);
    int*      ctr  = (int*)((char*)ws + XH_BYTES + WEXT_BYTES + PART_BYTES);

    xpack_kernel<<<dim3(XH_DIM + 1, NB), 192, 0, stream>>>(x, xh, ctr);
    conv_tail_kernel<<<dim3(4, NB), 512, 0, stream>>>(xh, cw, cb, gnw, gnb, scale,
                                                      wext, prt, ctr, out);
  } else {
    conv_mfma_kernel<<<dim3(16, NB), 256, 0, stream>>>(x, cw, cb, gnw, scale, ws);
    tail_kernel<<<dim3(16, NB), 256, 0, stream>>>(gnw, gnb, scale,
                                                  (const _Float16*)ws,
                                                  ws + OFF_PART_OLD, 16, out);
  }
}

// Round 10
// 195.103 us; speedup vs baseline: 1.7395x; 1.7395x over previous
//
#include <hip/hip_runtime.h>
#include <math.h>

typedef _Float16 f16x8 __attribute__((ext_vector_type(8)));
typedef _Float16 f16x4 __attribute__((ext_vector_type(4)));
typedef float f32x4 __attribute__((ext_vector_type(4)));
typedef float f32x2 __attribute__((ext_vector_type(2)));

#define CIN 8
#define HIN 128
#define WIN 128
#define OH 126
#define OW 126
#define COUT 64
#define NB 128
#define NGROUPS 16
#define CPG 4
#define PWN 31
#define XROWS 34
#define XH_DIM 130            // padded image (2 halo rows/cols of zeros)
#define TPIX (34*34)          // 1156 pixels per tile
#define XSPAD 3072            // R5's exact LDS geometry -> 2 blocks/CU

// ---- ws layout (bytes) ----
// xh f16 [b][iy][ix][ci] | wext f16 [b][wy][wx][c] | parts f32
#define XH_BYTES   ((size_t)NB*XH_DIM*XH_DIM*CIN*2)          // 34,611,200
#define WEXT_BYTES ((size_t)NB*PWN*PWN*COUT*2)               // 15,745,024
#define PART_BYTES ((size_t)NB*NGROUPS*4*2*4)                //     65,536
#define WS_NEEDED  (XH_BYTES + WEXT_BYTES + PART_BYTES)

// ---- old (fallback) ws layout ----
#define NPOOL (NB*PWN*PWN*COUT)
#define OFF_PART_OLD (NPOOL/2)   // f32 offset

// ============================================================
// R10 = R5's proven structure (167.2us total; conv 62us) with:
//  - packed-f32 stats/max epilogue (f32x2 -> v_pk_*): register-only.
//  - bf direct from global w (proven R7/R8).
//  - NO integer type-punning in the sbuf->wext path: R9's uint4 read
//    of _Float16 LDS was a strict-aliasing violation; TBAA can drop
//    the ds_write->ds_read lgkm dependency => timing-dependent stale
//    reads (R9: passed once, diverged under graph replay, absmax 1.0).
//    All reinterprets now use same-element f16x4 vector casts only.
// Cost model (solved R2/R5/R7/R8): harness fixed ~73us, xpack ~8,
// tail ~24, conv 62. Conv jointly DS/VALU/MFMA bound at effective
// clock -> this round cuts VALU issue slots only.
// ============================================================

// Pre-pack: x f32 NCHW -> xh f16 [b][iy][ix][ci] with zero halo.
__global__ __launch_bounds__(192)
void xpack_kernel(const float* __restrict__ x, _Float16* __restrict__ xh)
{
  const int iy = blockIdx.x;      // 0..129
  const int b  = blockIdx.y;
  const int ix = threadIdx.x;     // active < 130
  if (ix >= XH_DIM) return;
  f16x8 pk = {0,0,0,0,0,0,0,0};
  if (iy < HIN && ix < WIN) {
    const float* xb = x + (size_t)b*CIN*HIN*WIN + iy*WIN + ix;
    #pragma unroll
    for (int ci = 0; ci < 8; ++ci)
      pk[ci] = (_Float16)xb[ci*HIN*WIN];
  }
  *(f16x8*)&xh[(((size_t)b*XH_DIM + iy)*XH_DIM + ix)*CIN] = pk;
}

__global__ __launch_bounds__(512)
void conv_dma_kernel(const _Float16* __restrict__ xh,
                     const float* __restrict__ w,
                     const float* __restrict__ bias,
                     const float* __restrict__ gnw,
                     const float* __restrict__ scale,
                     _Float16* __restrict__ wext,
                     float* __restrict__ parts)
{
  __shared__ __align__(16) _Float16 xs[2][TPIX*8 + XSPAD]; // 2 x 24,640 B
  __shared__ __align__(16) _Float16 sbuf[8][256];          //   4,096 B
  __shared__ float red[8][16][2];                          //   1,024 B

  const int tid  = threadIdx.x;
  const int lane = tid & 63, wv = tid >> 6;     // 8 waves
  const int tx = blockIdx.x;                    // 0..3 (tile column)
  const int b  = blockIdx.y;
  const int ox0 = tx*32;
  const int q = lane >> 4, ln = lane & 15;

  // DMA one tile into xs[buf]: one f16x8 pixel per lane per instr.
  auto stage = [&](int buf, int ty) {
    const int oy0 = ty*32;
    #pragma unroll
    for (int k = 0; k < 3; ++k) {
      const int p = k*512 + tid;
      if (p < TPIX) {
        const int r = p / 34, c = p - r*34;
        const size_t gb = (((size_t)b*XH_DIM + (oy0 + r))*XH_DIM + (ox0 + c))*CIN;
        __builtin_amdgcn_global_load_lds(
            (const __attribute__((address_space(1))) void*)(xh + gb),
            (__attribute__((address_space(3))) void*)&xs[buf][p*8],
            16, 0, 0);
      }
    }
  };

  stage(0, 0);

  // B fragments straight from global w (L2-hot, once per block).
  f16x8 bf[4][3];
  #pragma unroll
  for (int nt = 0; nt < 4; ++nt) {
    const int n = nt*16 + ln;
    #pragma unroll
    for (int c = 0; c < 2; ++c) {
      const int khw = c*4 + q;
      #pragma unroll
      for (int ci = 0; ci < 8; ++ci)
        bf[nt][c][ci] = (_Float16)w[(n*CIN + ci)*9 + khw];
    }
    if (q == 0) {
      #pragma unroll
      for (int ci = 0; ci < 8; ++ci)
        bf[nt][2][ci] = (_Float16)w[(n*CIN + ci)*9 + 8];
    } else {
      bf[nt][2] = (f16x8){0,0,0,0,0,0,0,0};
    }
  }

  // strip A offsets: lane ln = x-offset m, quad q picks khw = c*4+q.
  int aoff[3];
  #pragma unroll
  for (int c = 0; c < 3; ++c) {
    const int khw = c*4 + q;               // 0..11
    const int ky = khw / 3, kx = khw - 3*(khw/3);
    aoff[c] = (khw < 9) ? (ky*34 + kx + ln)*8 : ln*8;  // padded taps -> B=0
  }

  float bias_r[4], sgn[4];
  f32x2 sg2[4];
  #pragma unroll
  for (int nt = 0; nt < 4; ++nt) {
    const int c = nt*16 + ln;
    bias_r[nt] = bias[c];
    sgn[nt] = (gnw[c]*scale[c] >= 0.f) ? 1.f : -1.f;  // GN slope sign (inv>0)
    sg2[nt] = (f32x2){sgn[nt], sgn[nt]};
  }

  f32x2 s2[4], sq2[4];
  #pragma unroll
  for (int nt = 0; nt < 4; ++nt) {
    s2[nt]  = (f32x2){0.f, 0.f};
    sq2[nt] = (f32x2){0.f, 0.f};
  }

  // stats x-mask: strip positions 14,15 (q==3, regs 2,3) are conv-x
  // 126,127 when tx==3 && bd==1 -> excluded.
  const float xm_hi = (q < 3) ? 1.f : 0.f;
  const f32x2 xm2 = (f32x2){xm_hi, xm_hi};

  asm volatile("s_waitcnt vmcnt(0)" ::: "memory");
  __syncthreads();

  for (int ty = 0; ty < 4; ++ty) {
    const int cur = ty & 1;
    if (ty < 3) stage(cur ^ 1, ty + 1);    // async prefetch next tile

    const int wy_g = ty*8 + wv;
    const int oy0  = ty*32;

    // 2 bands per wave (x0 = 0, 16); band = 4 strips = 4 pool windows
    #pragma unroll
    for (int bd = 0; bd < 2; ++bd) {
      const int x0 = bd << 4;
      const bool xedge = (tx == 3) && (bd == 1);

      f32x2 mx2[4];
      #pragma unroll
      for (int nt = 0; nt < 4; ++nt) mx2[nt] = (f32x2){-1e30f, -1e30f};

      #pragma unroll
      for (int sy = 0; sy < 4; ++sy) {
        const int y_l = wv*4 + sy;
        if (oy0 + y_l >= OH) break;        // uniform: only ty==3, wv==7, sy>=2
        const int base = (y_l*34 + x0)*8;

        f32x4 acc[4];
        #pragma unroll
        for (int nt = 0; nt < 4; ++nt) {
          const float bv = bias_r[nt];
          acc[nt] = (f32x4){bv, bv, bv, bv};  // bias as MFMA C operand
        }
        #pragma unroll
        for (int c = 0; c < 3; ++c) {
          const f16x8 a = *(const f16x8*)&xs[cur][base + aoff[c]];
          #pragma unroll
          for (int nt = 0; nt < 4; ++nt)
            acc[nt] = __builtin_amdgcn_mfma_f32_16x16x32_f16(a, bf[nt][c], acc[nt], 0, 0, 0);
        }

        // packed-f32 epilogue: stats + running window max (sign-domain)
        #pragma unroll
        for (int nt = 0; nt < 4; ++nt) {
          f32x2 p01 = (f32x2){acc[nt][0], acc[nt][1]};
          f32x2 p23 = (f32x2){acc[nt][2], acc[nt][3]};
          if (xedge) p23 *= xm2;           // mask conv-x 126,127
          s2[nt]  += p01 + p23;            // v_pk_add_f32
          sq2[nt] += p01*p01;              // v_pk_fma_f32
          sq2[nt] += p23*p23;
          const f32x2 a01 = sg2[nt]*p01;   // v_pk_mul_f32
          const f32x2 a23 = sg2[nt]*p23;
          mx2[nt].x = fmaxf(mx2[nt].x, fmaxf(a01.x, a23.x));
          mx2[nt].y = fmaxf(mx2[nt].y, fmaxf(a01.y, a23.y));
        }
      }

      // store band's 4 pooled windows: sbuf bounce -> coalesced store
      // (f16-typed accesses only; no integer type-punning — see header)
      if (wy_g < PWN) {
        #pragma unroll
        for (int nt = 0; nt < 4; ++nt) {
          const float m = fmaxf(mx2[nt].x, mx2[nt].y);
          sbuf[wv][q*64 + nt*16 + ln] = (_Float16)(sgn[nt]*m);
        }
        const int nw = xedge ? 3 : 4;      // window wx_g==31 dropped
        if (lane < nw*16) {
          const int wx0_g = tx*8 + (x0 >> 2);
          const f16x4 v = *(const f16x4*)&sbuf[wv][lane*4];
          *(f16x4*)&wext[(((size_t)b*PWN + wy_g)*PWN + wx0_g)*COUT + lane*4] = v;
        }
      }
    }

    if (ty < 3) {
      asm volatile("s_waitcnt vmcnt(0)" ::: "memory");  // next-tile DMA done
      __syncthreads();                                   // visible to all waves
    }
  }

  // combine packed accumulators, then per-wave stat reduce
  float s[4], sq[4];
  #pragma unroll
  for (int nt = 0; nt < 4; ++nt) {
    s[nt]  = s2[nt].x + s2[nt].y;
    sq[nt] = sq2[nt].x + sq2[nt].y;
  }
  #pragma unroll
  for (int nt = 0; nt < 4; ++nt) {
    float a = s[nt], c2 = sq[nt];
    a  += __shfl_xor(a, 16, 64);  a  += __shfl_xor(a, 32, 64);
    a  += __shfl_xor(a, 1, 64);   a  += __shfl_xor(a, 2, 64);
    c2 += __shfl_xor(c2, 16, 64); c2 += __shfl_xor(c2, 32, 64);
    c2 += __shfl_xor(c2, 1, 64);  c2 += __shfl_xor(c2, 2, 64);
    if (lane < 16 && (lane & 3) == 0) {
      red[wv][nt*4 + (ln >> 2)][0] = a;
      red[wv][nt*4 + (ln >> 2)][1] = c2;
    }
  }
  __syncthreads();
  if (tid < 32) {
    const int g = tid >> 1, k = tid & 1;
    float t = 0.f;
    #pragma unroll
    for (int w8 = 0; w8 < 8; ++w8) t += red[w8][g][k];
    parts[(((size_t)b*NGROUPS + g)*4 + tx)*2 + k] = t;
  }
}

// ============================================================
// Fallback conv (proven R0/R2 path, old ws layout; keeps bias).
// ============================================================
__global__ __launch_bounds__(256)
void conv_mfma_kernel(const float* __restrict__ x,
                      const float* __restrict__ w,
                      const float* __restrict__ bias,
                      const float* __restrict__ gnw,
                      const float* __restrict__ scale,
                      float* __restrict__ ws)
{
  __shared__ __align__(16) _Float16 xs[XROWS*34*8];
  __shared__ __align__(16) _Float16 wls[9*64*8];
  __shared__ float red[4][16][2];

  const int tid  = threadIdx.x;
  const int lane = tid & 63, wave = tid >> 6;
  const int tileIdx = blockIdx.x;
  const int tx = tileIdx & 3, ty = tileIdx >> 2;
  const int b  = blockIdx.y;
  const int ox0 = tx*32, oy0 = ty*32;

  for (int idx = tid; idx < 9*64*8; idx += 256) {
    const int ci = idx & 7, n = (idx >> 3) & 63, khw = idx >> 9;
    wls[idx] = (_Float16)w[(n*CIN + ci)*9 + khw];
  }
  const float* xb = x + (size_t)b * CIN*HIN*WIN;
  for (int p = tid; p < XROWS*34; p += 256) {
    const int r = p / 34, c = p - r*34;
    const int iy = oy0 + r, ix = ox0 + c;
    const bool ok = (iy < HIN) && (ix < WIN);
    const int gbase = iy*WIN + ix;
    f16x8 pk;
    #pragma unroll
    for (int ci = 0; ci < 8; ++ci) {
      const float v = ok ? xb[ci*HIN*WIN + gbase] : 0.f;
      pk[ci] = (_Float16)v;
    }
    *(f16x8*)&xs[p*8] = pk;
  }
  __syncthreads();

  const int q = lane >> 4, ln = lane & 15;
  f16x8 bf[4][3];
  #pragma unroll
  for (int nt = 0; nt < 4; ++nt) {
    #pragma unroll
    for (int c = 0; c < 2; ++c)
      bf[nt][c] = *(const f16x8*)&wls[((c*4 + q)*64 + nt*16 + ln)*8];
    if (q == 0) bf[nt][2] = *(const f16x8*)&wls[((8)*64 + nt*16 + ln)*8];
    else        bf[nt][2] = (f16x8){0,0,0,0,0,0,0,0};
  }
  const int dy = ln >> 2, dx = ln & 3;
  int aoff[3];
  #pragma unroll
  for (int c = 0; c < 3; ++c) {
    const int khw = c*4 + q;
    const int ky = khw / 3, kx = khw - 3*(khw/3);
    aoff[c] = (khw < 9) ? ((dy + ky)*34 + (dx + kx))*8 : 0;
  }
  float bias_r[4], sgn[4];
  #pragma unroll
  for (int nt = 0; nt < 4; ++nt) {
    const int c = nt*16 + ln;
    bias_r[nt] = bias[c];
    sgn[nt] = (gnw[c]*scale[c] >= 0.f) ? 1.f : -1.f;
  }
  float s[4]  = {0.f,0.f,0.f,0.f};
  float sq[4] = {0.f,0.f,0.f,0.f};
  _Float16* wext = (_Float16*)ws;

  #pragma unroll 2
  for (int i = 0; i < 16; ++i) {
    const int wyl = wave*2 + (i >> 3), wxl = i & 7;
    const int base = (wyl*4*34 + wxl*4)*8;
    f32x4 acc[4];
    #pragma unroll
    for (int nt = 0; nt < 4; ++nt) {
      const float bv = bias_r[nt];
      acc[nt] = (f32x4){bv, bv, bv, bv};
    }
    #pragma unroll
    for (int c = 0; c < 3; ++c) {
      const f16x8 a = *(const f16x8*)&xs[base + aoff[c]];
      #pragma unroll
      for (int nt = 0; nt < 4; ++nt)
        acc[nt] = __builtin_amdgcn_mfma_f32_16x16x32_f16(a, bf[nt][c], acc[nt], 0, 0, 0);
    }
    const int wyg = ty*8 + wyl, wxg = tx*8 + wxl;
    if ((wyg < PWN) && (wxg < PWN)) {
      const size_t rowbase = ((size_t)(b*PWN + wyg)*PWN + wxg)*COUT;
      float m4[4];
      #pragma unroll
      for (int nt = 0; nt < 4; ++nt) {
        const float v0 = acc[nt][0], v1 = acc[nt][1];
        const float v2 = acc[nt][2], v3 = acc[nt][3];
        s[nt]  += (v0+v1) + (v2+v3);
        sq[nt] += v0*v0 + v1*v1 + v2*v2 + v3*v3;
        const float sg = sgn[nt];
        float m = fmaxf(fmaxf(sg*v0, sg*v1), fmaxf(sg*v2, sg*v3));
        m = fmaxf(m, __shfl_xor(m, 16, 64));
        m = fmaxf(m, __shfl_xor(m, 32, 64));
        m4[nt] = sg*m;
      }
      float mv = m4[0];
      mv = (q == 1) ? m4[1] : mv;
      mv = (q == 2) ? m4[2] : mv;
      mv = (q == 3) ? m4[3] : mv;
      wext[rowbase + lane] = (_Float16)mv;
    } else {
      const bool yv = (wyg*4 + q) < OH;
      #pragma unroll
      for (int nt = 0; nt < 4; ++nt) {
        #pragma unroll
        for (int r = 0; r < 4; ++r) {
          const bool okp = yv && (wxg*4 + r < OW);
          const float v = okp ? acc[nt][r] : 0.f;
          s[nt] += v; sq[nt] += v*v;
        }
      }
    }
  }
  #pragma unroll
  for (int nt = 0; nt < 4; ++nt) {
    float a = s[nt], c2 = sq[nt];
    a  += __shfl_xor(a, 16, 64);  a  += __shfl_xor(a, 32, 64);
    a  += __shfl_xor(a, 1, 64);   a  += __shfl_xor(a, 2, 64);
    c2 += __shfl_xor(c2, 16, 64); c2 += __shfl_xor(c2, 32, 64);
    c2 += __shfl_xor(c2, 1, 64);  c2 += __shfl_xor(c2, 2, 64);
    if (lane < 16 && (lane & 3) == 0) {
      red[wave][nt*4 + (ln >> 2)][0] = a;
      red[wave][nt*4 + (ln >> 2)][1] = c2;
    }
  }
  __syncthreads();
  if (tid < 32) {
    const int g = tid >> 1, k = tid & 1;
    const float t = red[0][g][k] + red[1][g][k] + red[2][g][k] + red[3][g][k];
    ws[OFF_PART_OLD + (((size_t)b*NGROUPS + g)*16 + tileIdx)*2 + k] = t;
  }
}

// ============================================================
// Fused tail (parameterized partial count / pointers). R5-proven.
// ============================================================
__global__ __launch_bounds__(256)
void tail_kernel(const float* __restrict__ gnw,
                 const float* __restrict__ gnb,
                 const float* __restrict__ scale,
                 const _Float16* __restrict__ wext,
                 const float* __restrict__ parts,
                 const int nparts,
                 float* __restrict__ out)
{
  __shared__ float stat[NGROUPS*2];
  __shared__ float AB[128];
  __shared__ float vout[COUT*PWN];

  const int tid = threadIdx.x;
  const int xb  = blockIdx.x;
  const int b   = blockIdx.y;

  if (tid < 32) {
    const int g = tid >> 1, k = tid & 1;
    const float* p = parts + ((size_t)(b*NGROUPS + g)*nparts)*2 + k;
    float a = 0.f;
    for (int t = 0; t < nparts; ++t) a += p[t*2];
    stat[g*2 + k] = a;
  }
  __syncthreads();
  if (tid < COUT) {
    const int c = tid, g = c >> 2;
    const float N = (float)(CPG * OH * OW);
    const float mean = stat[g*2] / N;
    const float var  = stat[g*2 + 1] / N - mean*mean;
    const float inv  = rsqrtf(var + 1e-5f);
    const float ag   = inv * gnw[c];
    AB[c]      = ag * scale[c];
    AB[64 + c] = (gnb[c] - mean * ag) * scale[c];
  }
  __syncthreads();

  #pragma unroll
  for (int r = 0; r < 2; ++r) {
    const int wy = xb*2 + r;
    if (wy >= PWN) break;
    const size_t rb = (size_t)(b*PWN + wy)*PWN*COUT;

    if (tid < 248) {
      const f16x8 e = *(const f16x8*)&wext[rb + tid*8];
      const int wx = tid >> 3, c0 = (tid & 7)*8;
      #pragma unroll
      for (int j = 0; j < 8; ++j) {
        const int c = c0 + j;
        float v = fmaf(AB[c], (float)e[j], AB[64 + c]);
        v = fminf(fmaxf(v, 0.f), 1.f);
        vout[c*PWN + wx] = v;
      }
    }
    __syncthreads();
    for (int e = tid; e < COUT*PWN; e += 256) {
      const int c = e / PWN, wx = e - c*PWN;
      out[(((size_t)b*COUT + c)*PWN + wy)*PWN + wx] = vout[e];
    }
    __syncthreads();
  }
}

extern "C" void kernel_launch(void* const* d_in, const int* in_sizes, int n_in,
                              void* d_out, int out_size, void* d_ws, size_t ws_size,
                              hipStream_t stream)
{
  const float* x     = (const float*)d_in[0];
  const float* cw    = (const float*)d_in[1];
  const float* cb    = (const float*)d_in[2];
  const float* gnw   = (const float*)d_in[3];
  const float* gnb   = (const float*)d_in[4];
  const float* scale = (const float*)d_in[5];
  float* out = (float*)d_out;
  float* ws  = (float*)d_ws;

  if (ws_size >= WS_NEEDED) {
    _Float16* xh   = (_Float16*)ws;
    _Float16* wext = (_Float16*)((char*)ws + XH_BYTES);
    float*    prt  = (float*)((char*)ws + XH_BYTES + WEXT_BYTES);

    xpack_kernel<<<dim3(XH_DIM, NB), 192, 0, stream>>>(x, xh);
    conv_dma_kernel<<<dim3(4, NB), 512, 0, stream>>>(xh, cw, cb, gnw, scale, wext, prt);
    tail_kernel<<<dim3(16, NB), 256, 0, stream>>>(gnw, gnb, scale, wext, prt, 4, out);
  } else {
    conv_mfma_kernel<<<dim3(16, NB), 256, 0, stream>>>(x, cw, cb, gnw, scale, ws);
    tail_kernel<<<dim3(16, NB), 256, 0, stream>>>(gnw, gnb, scale,
                                                  (const _Float16*)ws,
                                                  ws + OFF_PART_OLD, 16, out);
  }
}

// Round 11
// 167.772 us; speedup vs baseline: 2.0228x; 1.1629x over previous
//
#include <hip/hip_runtime.h>
#include <math.h>

typedef _Float16 f16x8 __attribute__((ext_vector_type(8)));
typedef float f32x4 __attribute__((ext_vector_type(4)));

#define CIN 8
#define HIN 128
#define WIN 128
#define OH 126
#define OW 126
#define COUT 64
#define NB 128
#define NGROUPS 16
#define CPG 4
#define PWN 31
#define XROWS 34
#define XH_DIM 130            // padded image (2 halo rows/cols of zeros)
#define TPIX (34*34)          // 1156 pixels per tile
#define XSPAD 3072            // pads LDS to 54.4KB -> 2 blocks/CU -> VGPR budget 128

// ---- ws layout (bytes) ----
// xh f16 [b][iy][ix][ci] | wext f16 [b][wy][wx][c] | parts f32 | wh f16 [khw][n][ci]
#define XH_BYTES   ((size_t)NB*XH_DIM*XH_DIM*CIN*2)          // 34,611,200
#define WEXT_BYTES ((size_t)NB*PWN*PWN*COUT*2)               // 15,745,024
#define PART_BYTES ((size_t)NB*NGROUPS*4*2*4)                //     65,536
#define WH_BYTES   ((size_t)9*64*8*2)                        //      9,216
#define WS_NEEDED  (XH_BYTES + WEXT_BYTES + PART_BYTES + WH_BYTES)

// ---- old (fallback) ws layout ----
#define NPOOL (NB*PWN*PWN*COUT)
#define OFF_PART_OLD (NPOOL/2)   // f32 offset

// ============================================================
// R11 = byte-exact revert to R5 (best measured: 167.2us total,
// conv 62us, tight 61.6-62.5 spread). Post-R10 conclusion: conv at
// this structure is schedule/latency-bound, NOT issue-bound — R10 cut
// VALU busy 19.5->15.2us (packed f32x2 epilogue) and conv REGRESSED
// 62->75us; every conv-internal micro-opt since R5 was net-negative
// (R6 fail / R7 +37 / R8 +172 / R9 fail / R10 +13). Identical source
// -> identical codegen -> the measured-best configuration.
// ============================================================

// Pre-pack: x f32 NCHW -> xh f16 [b][iy][ix][ci] with zero halo;
// block XH_DIM additionally packs weights -> wh[khw][n][ci] f16.
__global__ __launch_bounds__(192)
void xpack_kernel(const float* __restrict__ x, const float* __restrict__ w,
                  _Float16* __restrict__ xh, _Float16* __restrict__ wh)
{
  const int iy = blockIdx.x;      // 0..129, 130 = weight block
  const int b  = blockIdx.y;
  if (iy == XH_DIM) {
    if (b != 0) return;
    for (int i = threadIdx.x; i < 9*64*8; i += 192) {
      const int khw = i >> 9, rem = i & 511;      // rem = n*8+ci
      wh[i] = (_Float16)w[rem*9 + khw];
    }
    return;
  }
  const int ix = threadIdx.x;     // active < 130
  if (ix >= XH_DIM) return;
  f16x8 pk = {0,0,0,0,0,0,0,0};
  if (iy < HIN && ix < WIN) {
    const float* xb = x + (size_t)b*CIN*HIN*WIN + iy*WIN + ix;
    #pragma unroll
    for (int ci = 0; ci < 8; ++ci)
      pk[ci] = (_Float16)xb[ci*HIN*WIN];
  }
  *(f16x8*)&xh[(((size_t)b*XH_DIM + iy)*XH_DIM + ix)*CIN] = pk;
}

// ============================================================
// Pipelined conv, strip-mapped (R3-verified lane map, in-lane
// pooling) inside the R4 DMA double-buffer structure.
//  - B fragments load from global wh (L2-hot), wls LDS deleted.
//  - strip mapping: pooling max is IN-LANE; no ds_bpermute per
//    window; store via tiny sbuf bounce.
//  - LDS padded to 54.4KB: 2 blocks/CU.
// ============================================================
__global__ __launch_bounds__(512)
void conv_dma_kernel(const _Float16* __restrict__ xh,
                     const _Float16* __restrict__ wh,
                     const float* __restrict__ bias,
                     const float* __restrict__ gnw,
                     const float* __restrict__ scale,
                     _Float16* __restrict__ wext,
                     float* __restrict__ parts)
{
  __shared__ __align__(16) _Float16 xs[2][TPIX*8 + XSPAD]; // 2 x 24,640 B
  __shared__ __align__(8)  _Float16 sbuf[8][256];          //   4,096 B
  __shared__ float red[8][16][2];                          //   1,024 B

  const int tid  = threadIdx.x;
  const int lane = tid & 63, wv = tid >> 6;     // 8 waves
  const int tx = blockIdx.x;                    // 0..3 (tile column)
  const int b  = blockIdx.y;
  const int ox0 = tx*32;

  const int q = lane >> 4, ln = lane & 15;

  // DMA one tile into xs[buf]: one f16x8 pixel per lane per instr.
  auto stage = [&](int buf, int ty) {
    const int oy0 = ty*32;
    #pragma unroll
    for (int k = 0; k < 3; ++k) {
      const int p = k*512 + tid;
      if (p < TPIX) {
        const int r = p / 34, c = p - r*34;
        const size_t gb = (((size_t)b*XH_DIM + (oy0 + r))*XH_DIM + (ox0 + c))*CIN;
        __builtin_amdgcn_global_load_lds(
            (const __attribute__((address_space(1))) void*)(xh + gb),
            (__attribute__((address_space(3))) void*)&xs[buf][p*8],
            16, 0, 0);
      }
    }
  };

  stage(0, 0);

  // B fragments straight from global (L2-hot, 9KB total, broadcast).
  f16x8 bf[4][3];
  #pragma unroll
  for (int nt = 0; nt < 4; ++nt) {
    #pragma unroll
    for (int c = 0; c < 2; ++c)
      bf[nt][c] = *(const f16x8*)&wh[((c*4 + q)*64 + nt*16 + ln)*8];
    if (q == 0)
      bf[nt][2] = *(const f16x8*)&wh[((8)*64 + nt*16 + ln)*8];
    else
      bf[nt][2] = (f16x8){0,0,0,0,0,0,0,0};
  }

  // strip A offsets: lane ln = x-offset m, quad q picks khw = c*4+q.
  int aoff[3];
  #pragma unroll
  for (int c = 0; c < 3; ++c) {
    const int khw = c*4 + q;               // 0..11
    const int ky = khw / 3, kx = khw - 3*(khw/3);
    aoff[c] = (khw < 9) ? (ky*34 + kx + ln)*8 : ln*8;  // padded taps -> B=0
  }

  float bias_r[4], sgn[4];
  #pragma unroll
  for (int nt = 0; nt < 4; ++nt) {
    const int c = nt*16 + ln;
    bias_r[nt] = bias[c];
    sgn[nt] = (gnw[c]*scale[c] >= 0.f) ? 1.f : -1.f;  // GN slope sign (inv>0)
  }

  float s[4]  = {0.f,0.f,0.f,0.f};
  float sq[4] = {0.f,0.f,0.f,0.f};

  // stats x-mask: strip positions 14,15 (q==3, regs 2,3) are conv-x
  // 126,127 when tx==3 && bd==1 -> excluded.
  const float xm_hi = (q < 3) ? 1.f : 0.f;

  asm volatile("s_waitcnt vmcnt(0)" ::: "memory");
  __syncthreads();

  for (int ty = 0; ty < 4; ++ty) {
    const int cur = ty & 1;
    if (ty < 3) stage(cur ^ 1, ty + 1);    // async prefetch next tile

    const int wy_g = ty*8 + wv;
    const int oy0  = ty*32;

    // 2 bands per wave (x0 = 0, 16); band = 4 strips = 4 pool windows
    #pragma unroll
    for (int bd = 0; bd < 2; ++bd) {
      const int x0 = bd << 4;
      const bool xedge = (tx == 3) && (bd == 1);

      float mx[4] = {-1e30f, -1e30f, -1e30f, -1e30f};

      #pragma unroll
      for (int sy = 0; sy < 4; ++sy) {
        const int y_l = wv*4 + sy;
        if (oy0 + y_l >= OH) break;        // uniform: only ty==3, wv==7, sy>=2
        const int base = (y_l*34 + x0)*8;

        f32x4 acc[4];
        #pragma unroll
        for (int nt = 0; nt < 4; ++nt) {
          const float bv = bias_r[nt];
          acc[nt] = (f32x4){bv, bv, bv, bv};  // bias as MFMA C operand
        }
        #pragma unroll
        for (int c = 0; c < 3; ++c) {
          const f16x8 a = *(const f16x8*)&xs[cur][base + aoff[c]];
          #pragma unroll
          for (int nt = 0; nt < 4; ++nt)
            acc[nt] = __builtin_amdgcn_mfma_f32_16x16x32_f16(a, bf[nt][c], acc[nt], 0, 0, 0);
        }

        // fully in-lane: stats + running window max (sign-domain)
        #pragma unroll
        for (int nt = 0; nt < 4; ++nt) {
          float v0 = acc[nt][0], v1 = acc[nt][1];
          float v2 = acc[nt][2], v3 = acc[nt][3];
          if (xedge) { v2 *= xm_hi; v3 *= xm_hi; }   // mask conv-x 126,127
          s[nt]  += (v0+v1) + (v2+v3);
          sq[nt] += v0*v0 + v1*v1 + v2*v2 + v3*v3;
          const float sg = sgn[nt];
          const float m = fmaxf(fmaxf(sg*v0, sg*v1), fmaxf(sg*v2, sg*v3));
          mx[nt] = fmaxf(mx[nt], m);
        }
      }

      // store band's 4 pooled windows: sbuf bounce -> coalesced store
      if (wy_g < PWN) {
        #pragma unroll
        for (int nt = 0; nt < 4; ++nt)
          sbuf[wv][q*64 + nt*16 + ln] = (_Float16)(sgn[nt]*mx[nt]);
        const int nw = xedge ? 3 : 4;      // window wx_g==31 dropped
        if (lane < nw*16) {
          const int wx0_g = tx*8 + (x0 >> 2);
          const uint2 v = *(const uint2*)&sbuf[wv][lane*4];
          *(uint2*)&wext[(((size_t)b*PWN + wy_g)*PWN + wx0_g)*COUT + lane*4] = v;
        }
      }
    }

    if (ty < 3) {
      asm volatile("s_waitcnt vmcnt(0)" ::: "memory");  // next tile DMA done
      __syncthreads();                                   // visible to all waves
    }
  }

  // per-wave stat reduce: quads (xor 16,32) then channels-in-group (xor 1,2)
  #pragma unroll
  for (int nt = 0; nt < 4; ++nt) {
    float a = s[nt], c2 = sq[nt];
    a  += __shfl_xor(a, 16, 64);  a  += __shfl_xor(a, 32, 64);
    a  += __shfl_xor(a, 1, 64);   a  += __shfl_xor(a, 2, 64);
    c2 += __shfl_xor(c2, 16, 64); c2 += __shfl_xor(c2, 32, 64);
    c2 += __shfl_xor(c2, 1, 64);  c2 += __shfl_xor(c2, 2, 64);
    if (lane < 16 && (lane & 3) == 0) {
      red[wv][nt*4 + (ln >> 2)][0] = a;
      red[wv][nt*4 + (ln >> 2)][1] = c2;
    }
  }
  __syncthreads();
  if (tid < 32) {
    const int g = tid >> 1, k = tid & 1;
    float t = 0.f;
    #pragma unroll
    for (int w8 = 0; w8 < 8; ++w8) t += red[w8][g][k];
    parts[(((size_t)b*NGROUPS + g)*4 + tx)*2 + k] = t;
  }
}

// ============================================================
// Fallback conv (proven R0/R2 path, old ws layout).
// ============================================================
__global__ __launch_bounds__(256)
void conv_mfma_kernel(const float* __restrict__ x,
                      const float* __restrict__ w,
                      const float* __restrict__ bias,
                      const float* __restrict__ gnw,
                      const float* __restrict__ scale,
                      float* __restrict__ ws)
{
  __shared__ __align__(16) _Float16 xs[XROWS*34*8];
  __shared__ __align__(16) _Float16 wls[9*64*8];
  __shared__ float red[4][16][2];

  const int tid  = threadIdx.x;
  const int lane = tid & 63, wave = tid >> 6;
  const int tileIdx = blockIdx.x;
  const int tx = tileIdx & 3, ty = tileIdx >> 2;
  const int b  = blockIdx.y;
  const int ox0 = tx*32, oy0 = ty*32;

  for (int idx = tid; idx < 9*64*8; idx += 256) {
    const int ci = idx & 7, n = (idx >> 3) & 63, khw = idx >> 9;
    wls[idx] = (_Float16)w[(n*CIN + ci)*9 + khw];
  }
  const float* xb = x + (size_t)b * CIN*HIN*WIN;
  for (int p = tid; p < XROWS*34; p += 256) {
    const int r = p / 34, c = p - r*34;
    const int iy = oy0 + r, ix = ox0 + c;
    const bool ok = (iy < HIN) && (ix < WIN);
    const int gbase = iy*WIN + ix;
    f16x8 pk;
    #pragma unroll
    for (int ci = 0; ci < 8; ++ci) {
      const float v = ok ? xb[ci*HIN*WIN + gbase] : 0.f;
      pk[ci] = (_Float16)v;
    }
    *(f16x8*)&xs[p*8] = pk;
  }
  __syncthreads();

  const int q = lane >> 4, ln = lane & 15;
  f16x8 bf[4][3];
  #pragma unroll
  for (int nt = 0; nt < 4; ++nt) {
    #pragma unroll
    for (int c = 0; c < 2; ++c)
      bf[nt][c] = *(const f16x8*)&wls[((c*4 + q)*64 + nt*16 + ln)*8];
    if (q == 0) bf[nt][2] = *(const f16x8*)&wls[((8)*64 + nt*16 + ln)*8];
    else        bf[nt][2] = (f16x8){0,0,0,0,0,0,0,0};
  }
  const int dy = ln >> 2, dx = ln & 3;
  int aoff[3];
  #pragma unroll
  for (int c = 0; c < 3; ++c) {
    const int khw = c*4 + q;
    const int ky = khw / 3, kx = khw - 3*(khw/3);
    aoff[c] = (khw < 9) ? ((dy + ky)*34 + (dx + kx))*8 : 0;
  }
  float bias_r[4], sgn[4];
  #pragma unroll
  for (int nt = 0; nt < 4; ++nt) {
    const int c = nt*16 + ln;
    bias_r[nt] = bias[c];
    sgn[nt] = (gnw[c]*scale[c] >= 0.f) ? 1.f : -1.f;
  }
  float s[4]  = {0.f,0.f,0.f,0.f};
  float sq[4] = {0.f,0.f,0.f,0.f};
  _Float16* wext = (_Float16*)ws;

  #pragma unroll 2
  for (int i = 0; i < 16; ++i) {
    const int wyl = wave*2 + (i >> 3), wxl = i & 7;
    const int base = (wyl*4*34 + wxl*4)*8;
    f32x4 acc[4];
    #pragma unroll
    for (int nt = 0; nt < 4; ++nt) {
      const float bv = bias_r[nt];
      acc[nt] = (f32x4){bv, bv, bv, bv};
    }
    #pragma unroll
    for (int c = 0; c < 3; ++c) {
      const f16x8 a = *(const f16x8*)&xs[base + aoff[c]];
      #pragma unroll
      for (int nt = 0; nt < 4; ++nt)
        acc[nt] = __builtin_amdgcn_mfma_f32_16x16x32_f16(a, bf[nt][c], acc[nt], 0, 0, 0);
    }
    const int wyg = ty*8 + wyl, wxg = tx*8 + wxl;
    if ((wyg < PWN) && (wxg < PWN)) {
      const size_t rowbase = ((size_t)(b*PWN + wyg)*PWN + wxg)*COUT;
      float m4[4];
      #pragma unroll
      for (int nt = 0; nt < 4; ++nt) {
        const float v0 = acc[nt][0], v1 = acc[nt][1];
        const float v2 = acc[nt][2], v3 = acc[nt][3];
        s[nt]  += (v0+v1) + (v2+v3);
        sq[nt] += v0*v0 + v1*v1 + v2*v2 + v3*v3;
        const float sg = sgn[nt];
        float m = fmaxf(fmaxf(sg*v0, sg*v1), fmaxf(sg*v2, sg*v3));
        m = fmaxf(m, __shfl_xor(m, 16, 64));
        m = fmaxf(m, __shfl_xor(m, 32, 64));
        m4[nt] = sg*m;
      }
      float mv = m4[0];
      mv = (q == 1) ? m4[1] : mv;
      mv = (q == 2) ? m4[2] : mv;
      mv = (q == 3) ? m4[3] : mv;
      wext[rowbase + lane] = (_Float16)mv;
    } else {
      const bool yv = (wyg*4 + q) < OH;
      #pragma unroll
      for (int nt = 0; nt < 4; ++nt) {
        #pragma unroll
        for (int r = 0; r < 4; ++r) {
          const bool okp = yv && (wxg*4 + r < OW);
          const float v = okp ? acc[nt][r] : 0.f;
          s[nt] += v; sq[nt] += v*v;
        }
      }
    }
  }
  #pragma unroll
  for (int nt = 0; nt < 4; ++nt) {
    float a = s[nt], c2 = sq[nt];
    a  += __shfl_xor(a, 16, 64);  a  += __shfl_xor(a, 32, 64);
    a  += __shfl_xor(a, 1, 64);   a  += __shfl_xor(a, 2, 64);
    c2 += __shfl_xor(c2, 16, 64); c2 += __shfl_xor(c2, 32, 64);
    c2 += __shfl_xor(c2, 1, 64);  c2 += __shfl_xor(c2, 2, 64);
    if (lane < 16 && (lane & 3) == 0) {
      red[wave][nt*4 + (ln >> 2)][0] = a;
      red[wave][nt*4 + (ln >> 2)][1] = c2;
    }
  }
  __syncthreads();
  if (tid < 32) {
    const int g = tid >> 1, k = tid & 1;
    const float t = red[0][g][k] + red[1][g][k] + red[2][g][k] + red[3][g][k];
    ws[OFF_PART_OLD + (((size_t)b*NGROUPS + g)*16 + tileIdx)*2 + k] = t;
  }
}

// ============================================================
// Fused tail (parameterized partial count / pointers).
// ============================================================
__global__ __launch_bounds__(256)
void tail_kernel(const float* __restrict__ gnw,
                 const float* __restrict__ gnb,
                 const float* __restrict__ scale,
                 const _Float16* __restrict__ wext,
                 const float* __restrict__ parts,
                 const int nparts,
                 float* __restrict__ out)
{
  __shared__ float stat[NGROUPS*2];
  __shared__ float AB[128];
  __shared__ float vout[COUT*PWN];

  const int tid = threadIdx.x;
  const int xb  = blockIdx.x;
  const int b   = blockIdx.y;

  if (tid < 32) {
    const int g = tid >> 1, k = tid & 1;
    const float* p = parts + ((size_t)(b*NGROUPS + g)*nparts)*2 + k;
    float a = 0.f;
    for (int t = 0; t < nparts; ++t) a += p[t*2];
    stat[g*2 + k] = a;
  }
  __syncthreads();
  if (tid < COUT) {
    const int c = tid, g = c >> 2;
    const float N = (float)(CPG * OH * OW);
    const float mean = stat[g*2] / N;
    const float var  = stat[g*2 + 1] / N - mean*mean;
    const float inv  = rsqrtf(var + 1e-5f);
    const float ag   = inv * gnw[c];
    AB[c]      = ag * scale[c];
    AB[64 + c] = (gnb[c] - mean * ag) * scale[c];
  }
  __syncthreads();

  #pragma unroll
  for (int r = 0; r < 2; ++r) {
    const int wy = xb*2 + r;
    if (wy >= PWN) break;
    const size_t rb = (size_t)(b*PWN + wy)*PWN*COUT;

    if (tid < 248) {
      const f16x8 e = *(const f16x8*)&wext[rb + tid*8];
      const int wx = tid >> 3, c0 = (tid & 7)*8;
      #pragma unroll
      for (int j = 0; j < 8; ++j) {
        const int c = c0 + j;
        float v = fmaf(AB[c], (float)e[j], AB[64 + c]);
        v = fminf(fmaxf(v, 0.f), 1.f);
        vout[c*PWN + wx] = v;
      }
    }
    __syncthreads();
    for (int e = tid; e < COUT*PWN; e += 256) {
      const int c = e / PWN, wx = e - c*PWN;
      out[(((size_t)b*COUT + c)*PWN + wy)*PWN + wx] = vout[e];
    }
    __syncthreads();
  }
}

extern "C" void kernel_launch(void* const* d_in, const int* in_sizes, int n_in,
                              void* d_out, int out_size, void* d_ws, size_t ws_size,
                              hipStream_t stream)
{
  const float* x     = (const float*)d_in[0];
  const float* cw    = (const float*)d_in[1];
  const float* cb    = (const float*)d_in[2];
  const float* gnw   = (const float*)d_in[3];
  const float* gnb   = (const float*)d_in[4];
  const float* scale = (const float*)d_in[5];
  float* out = (float*)d_out;
  float* ws  = (float*)d_ws;

  if (ws_size >= WS_NEEDED) {
    _Float16* xh   = (_Float16*)ws;
    _Float16* wext = (_Float16*)((char*)ws + XH_BYTES);
    float*    prt  = (float*)((char*)ws + XH_BYTES + WEXT_BYTES);
    _Float16* wh   = (_Float16*)((char*)ws + XH_BYTES + WEXT_BYTES + PART_BYTES);

    xpack_kernel<<<dim3(XH_DIM + 1, NB), 192, 0, stream>>>(x, cw, xh, wh);
    conv_dma_kernel<<<dim3(4, NB), 512, 0, stream>>>(xh, wh, cb, gnw, scale, wext, prt);
    tail_kernel<<<dim3(16, NB), 256, 0, stream>>>(gnw, gnb, scale, wext, prt, 4, out);
  } else {
    conv_mfma_kernel<<<dim3(16, NB), 256, 0, stream>>>(x, cw, cb, gnw, scale, ws);
    tail_kernel<<<dim3(16, NB), 256, 0, stream>>>(gnw, gnb, scale,
                                                  (const _Float16*)ws,
                                                  ws + OFF_PART_OLD, 16, out);
  }
}

// Round 12
// 163.805 us; speedup vs baseline: 2.0718x; 1.0242x over previous
//
#include <hip/hip_runtime.h>
#include <math.h>

typedef _Float16 f16x8 __attribute__((ext_vector_type(8)));
typedef float f32x4 __attribute__((ext_vector_type(4)));

#define CIN 8
#define HIN 128
#define WIN 128
#define OH 126
#define OW 126
#define COUT 64
#define NB 128
#define NGROUPS 16
#define CPG 4
#define PWN 31
#define XROWS 34
#define XH_DIM 130            // padded image (2 halo rows/cols of zeros)
#define TPIX (34*34)          // 1156 pixels per tile
#define XSPAD 3072            // pads LDS to 54.4KB -> 2 blocks/CU -> VGPR budget 128

// ---- ws layout (bytes) ----
// xh f16 [b][iy][ix][ci] | wext f16 [b][wy][wx][c] | parts f32 | wh f16 [khw][n][ci]
#define XH_BYTES   ((size_t)NB*XH_DIM*XH_DIM*CIN*2)          // 34,611,200
#define WEXT_BYTES ((size_t)NB*PWN*PWN*COUT*2)               // 15,745,024
#define PART_BYTES ((size_t)NB*NGROUPS*4*2*4)                //     65,536
#define WH_BYTES   ((size_t)9*64*8*2)                        //      9,216
#define WS_NEEDED  (XH_BYTES + WEXT_BYTES + PART_BYTES + WH_BYTES)

// ---- old (fallback) ws layout ----
#define NPOOL (NB*PWN*PWN*COUT)
#define OFF_PART_OLD (NPOOL/2)   // f32 offset

// ============================================================
// R12 = R11 (measured 167.8us; R5 structure measured 167.2 — the
// twice-confirmed best) with ONE change: tail-only surgery.
// Calibration from R11: rocprof per-kernel durations vary ~30%
// across sessions on identical binaries (profile runs vs timed
// graph-replay clocks differ); only timed totals are comparable.
// conv/xpack are byte-identical to R11's source here.
// New tail: both rows' gathers issued up front (2x MLP, latency
// paid once), single vout[2][] LDS transpose buffer, ONE barrier
// before a combined store sweep: 6 syncthreads/block -> 3.
// Null result (+-2us) => tail is small at timed clock => structure
// is at its practical plateau.
// ============================================================

// Pre-pack: x f32 NCHW -> xh f16 [b][iy][ix][ci] with zero halo;
// block XH_DIM additionally packs weights -> wh[khw][n][ci] f16.
__global__ __launch_bounds__(192)
void xpack_kernel(const float* __restrict__ x, const float* __restrict__ w,
                  _Float16* __restrict__ xh, _Float16* __restrict__ wh)
{
  const int iy = blockIdx.x;      // 0..129, 130 = weight block
  const int b  = blockIdx.y;
  if (iy == XH_DIM) {
    if (b != 0) return;
    for (int i = threadIdx.x; i < 9*64*8; i += 192) {
      const int khw = i >> 9, rem = i & 511;      // rem = n*8+ci
      wh[i] = (_Float16)w[rem*9 + khw];
    }
    return;
  }
  const int ix = threadIdx.x;     // active < 130
  if (ix >= XH_DIM) return;
  f16x8 pk = {0,0,0,0,0,0,0,0};
  if (iy < HIN && ix < WIN) {
    const float* xb = x + (size_t)b*CIN*HIN*WIN + iy*WIN + ix;
    #pragma unroll
    for (int ci = 0; ci < 8; ++ci)
      pk[ci] = (_Float16)xb[ci*HIN*WIN];
  }
  *(f16x8*)&xh[(((size_t)b*XH_DIM + iy)*XH_DIM + ix)*CIN] = pk;
}

// ============================================================
// Pipelined conv, strip-mapped (R3-verified lane map, in-lane
// pooling) inside the R4 DMA double-buffer structure.
//  - B fragments load from global wh (L2-hot), wls LDS deleted.
//  - strip mapping: pooling max is IN-LANE; no ds_bpermute per
//    window; store via tiny sbuf bounce.
//  - LDS padded to 54.4KB: 2 blocks/CU.
// BYTE-IDENTICAL to R11 (measured-best). Do not perturb.
// ============================================================
__global__ __launch_bounds__(512)
void conv_dma_kernel(const _Float16* __restrict__ xh,
                     const _Float16* __restrict__ wh,
                     const float* __restrict__ bias,
                     const float* __restrict__ gnw,
                     const float* __restrict__ scale,
                     _Float16* __restrict__ wext,
                     float* __restrict__ parts)
{
  __shared__ __align__(16) _Float16 xs[2][TPIX*8 + XSPAD]; // 2 x 24,640 B
  __shared__ __align__(8)  _Float16 sbuf[8][256];          //   4,096 B
  __shared__ float red[8][16][2];                          //   1,024 B

  const int tid  = threadIdx.x;
  const int lane = tid & 63, wv = tid >> 6;     // 8 waves
  const int tx = blockIdx.x;                    // 0..3 (tile column)
  const int b  = blockIdx.y;
  const int ox0 = tx*32;

  const int q = lane >> 4, ln = lane & 15;

  // DMA one tile into xs[buf]: one f16x8 pixel per lane per instr.
  auto stage = [&](int buf, int ty) {
    const int oy0 = ty*32;
    #pragma unroll
    for (int k = 0; k < 3; ++k) {
      const int p = k*512 + tid;
      if (p < TPIX) {
        const int r = p / 34, c = p - r*34;
        const size_t gb = (((size_t)b*XH_DIM + (oy0 + r))*XH_DIM + (ox0 + c))*CIN;
        __builtin_amdgcn_global_load_lds(
            (const __attribute__((address_space(1))) void*)(xh + gb),
            (__attribute__((address_space(3))) void*)&xs[buf][p*8],
            16, 0, 0);
      }
    }
  };

  stage(0, 0);

  // B fragments straight from global (L2-hot, 9KB total, broadcast).
  f16x8 bf[4][3];
  #pragma unroll
  for (int nt = 0; nt < 4; ++nt) {
    #pragma unroll
    for (int c = 0; c < 2; ++c)
      bf[nt][c] = *(const f16x8*)&wh[((c*4 + q)*64 + nt*16 + ln)*8];
    if (q == 0)
      bf[nt][2] = *(const f16x8*)&wh[((8)*64 + nt*16 + ln)*8];
    else
      bf[nt][2] = (f16x8){0,0,0,0,0,0,0,0};
  }

  // strip A offsets: lane ln = x-offset m, quad q picks khw = c*4+q.
  int aoff[3];
  #pragma unroll
  for (int c = 0; c < 3; ++c) {
    const int khw = c*4 + q;               // 0..11
    const int ky = khw / 3, kx = khw - 3*(khw/3);
    aoff[c] = (khw < 9) ? (ky*34 + kx + ln)*8 : ln*8;  // padded taps -> B=0
  }

  float bias_r[4], sgn[4];
  #pragma unroll
  for (int nt = 0; nt < 4; ++nt) {
    const int c = nt*16 + ln;
    bias_r[nt] = bias[c];
    sgn[nt] = (gnw[c]*scale[c] >= 0.f) ? 1.f : -1.f;  // GN slope sign (inv>0)
  }

  float s[4]  = {0.f,0.f,0.f,0.f};
  float sq[4] = {0.f,0.f,0.f,0.f};

  // stats x-mask: strip positions 14,15 (q==3, regs 2,3) are conv-x
  // 126,127 when tx==3 && bd==1 -> excluded.
  const float xm_hi = (q < 3) ? 1.f : 0.f;

  asm volatile("s_waitcnt vmcnt(0)" ::: "memory");
  __syncthreads();

  for (int ty = 0; ty < 4; ++ty) {
    const int cur = ty & 1;
    if (ty < 3) stage(cur ^ 1, ty + 1);    // async prefetch next tile

    const int wy_g = ty*8 + wv;
    const int oy0  = ty*32;

    // 2 bands per wave (x0 = 0, 16); band = 4 strips = 4 pool windows
    #pragma unroll
    for (int bd = 0; bd < 2; ++bd) {
      const int x0 = bd << 4;
      const bool xedge = (tx == 3) && (bd == 1);

      float mx[4] = {-1e30f, -1e30f, -1e30f, -1e30f};

      #pragma unroll
      for (int sy = 0; sy < 4; ++sy) {
        const int y_l = wv*4 + sy;
        if (oy0 + y_l >= OH) break;        // uniform: only ty==3, wv==7, sy>=2
        const int base = (y_l*34 + x0)*8;

        f32x4 acc[4];
        #pragma unroll
        for (int nt = 0; nt < 4; ++nt) {
          const float bv = bias_r[nt];
          acc[nt] = (f32x4){bv, bv, bv, bv};  // bias as MFMA C operand
        }
        #pragma unroll
        for (int c = 0; c < 3; ++c) {
          const f16x8 a = *(const f16x8*)&xs[cur][base + aoff[c]];
          #pragma unroll
          for (int nt = 0; nt < 4; ++nt)
            acc[nt] = __builtin_amdgcn_mfma_f32_16x16x32_f16(a, bf[nt][c], acc[nt], 0, 0, 0);
        }

        // fully in-lane: stats + running window max (sign-domain)
        #pragma unroll
        for (int nt = 0; nt < 4; ++nt) {
          float v0 = acc[nt][0], v1 = acc[nt][1];
          float v2 = acc[nt][2], v3 = acc[nt][3];
          if (xedge) { v2 *= xm_hi; v3 *= xm_hi; }   // mask conv-x 126,127
          s[nt]  += (v0+v1) + (v2+v3);
          sq[nt] += v0*v0 + v1*v1 + v2*v2 + v3*v3;
          const float sg = sgn[nt];
          const float m = fmaxf(fmaxf(sg*v0, sg*v1), fmaxf(sg*v2, sg*v3));
          mx[nt] = fmaxf(mx[nt], m);
        }
      }

      // store band's 4 pooled windows: sbuf bounce -> coalesced store
      if (wy_g < PWN) {
        #pragma unroll
        for (int nt = 0; nt < 4; ++nt)
          sbuf[wv][q*64 + nt*16 + ln] = (_Float16)(sgn[nt]*mx[nt]);
        const int nw = xedge ? 3 : 4;      // window wx_g==31 dropped
        if (lane < nw*16) {
          const int wx0_g = tx*8 + (x0 >> 2);
          const uint2 v = *(const uint2*)&sbuf[wv][lane*4];
          *(uint2*)&wext[(((size_t)b*PWN + wy_g)*PWN + wx0_g)*COUT + lane*4] = v;
        }
      }
    }

    if (ty < 3) {
      asm volatile("s_waitcnt vmcnt(0)" ::: "memory");  // next tile DMA done
      __syncthreads();                                   // visible to all waves
    }
  }

  // per-wave stat reduce: quads (xor 16,32) then channels-in-group (xor 1,2)
  #pragma unroll
  for (int nt = 0; nt < 4; ++nt) {
    float a = s[nt], c2 = sq[nt];
    a  += __shfl_xor(a, 16, 64);  a  += __shfl_xor(a, 32, 64);
    a  += __shfl_xor(a, 1, 64);   a  += __shfl_xor(a, 2, 64);
    c2 += __shfl_xor(c2, 16, 64); c2 += __shfl_xor(c2, 32, 64);
    c2 += __shfl_xor(c2, 1, 64);  c2 += __shfl_xor(c2, 2, 64);
    if (lane < 16 && (lane & 3) == 0) {
      red[wv][nt*4 + (ln >> 2)][0] = a;
      red[wv][nt*4 + (ln >> 2)][1] = c2;
    }
  }
  __syncthreads();
  if (tid < 32) {
    const int g = tid >> 1, k = tid & 1;
    float t = 0.f;
    #pragma unroll
    for (int w8 = 0; w8 < 8; ++w8) t += red[w8][g][k];
    parts[(((size_t)b*NGROUPS + g)*4 + tx)*2 + k] = t;
  }
}

// ============================================================
// Fallback conv (proven R0/R2 path, old ws layout).
// ============================================================
__global__ __launch_bounds__(256)
void conv_mfma_kernel(const float* __restrict__ x,
                      const float* __restrict__ w,
                      const float* __restrict__ bias,
                      const float* __restrict__ gnw,
                      const float* __restrict__ scale,
                      float* __restrict__ ws)
{
  __shared__ __align__(16) _Float16 xs[XROWS*34*8];
  __shared__ __align__(16) _Float16 wls[9*64*8];
  __shared__ float red[4][16][2];

  const int tid  = threadIdx.x;
  const int lane = tid & 63, wave = tid >> 6;
  const int tileIdx = blockIdx.x;
  const int tx = tileIdx & 3, ty = tileIdx >> 2;
  const int b  = blockIdx.y;
  const int ox0 = tx*32, oy0 = ty*32;

  for (int idx = tid; idx < 9*64*8; idx += 256) {
    const int ci = idx & 7, n = (idx >> 3) & 63, khw = idx >> 9;
    wls[idx] = (_Float16)w[(n*CIN + ci)*9 + khw];
  }
  const float* xb = x + (size_t)b * CIN*HIN*WIN;
  for (int p = tid; p < XROWS*34; p += 256) {
    const int r = p / 34, c = p - r*34;
    const int iy = oy0 + r, ix = ox0 + c;
    const bool ok = (iy < HIN) && (ix < WIN);
    const int gbase = iy*WIN + ix;
    f16x8 pk;
    #pragma unroll
    for (int ci = 0; ci < 8; ++ci) {
      const float v = ok ? xb[ci*HIN*WIN + gbase] : 0.f;
      pk[ci] = (_Float16)v;
    }
    *(f16x8*)&xs[p*8] = pk;
  }
  __syncthreads();

  const int q = lane >> 4, ln = lane & 15;
  f16x8 bf[4][3];
  #pragma unroll
  for (int nt = 0; nt < 4; ++nt) {
    #pragma unroll
    for (int c = 0; c < 2; ++c)
      bf[nt][c] = *(const f16x8*)&wls[((c*4 + q)*64 + nt*16 + ln)*8];
    if (q == 0) bf[nt][2] = *(const f16x8*)&wls[((8)*64 + nt*16 + ln)*8];
    else        bf[nt][2] = (f16x8){0,0,0,0,0,0,0,0};
  }
  const int dy = ln >> 2, dx = ln & 3;
  int aoff[3];
  #pragma unroll
  for (int c = 0; c < 3; ++c) {
    const int khw = c*4 + q;
    const int ky = khw / 3, kx = khw - 3*(khw/3);
    aoff[c] = (khw < 9) ? ((dy + ky)*34 + (dx + kx))*8 : 0;
  }
  float bias_r[4], sgn[4];
  #pragma unroll
  for (int nt = 0; nt < 4; ++nt) {
    const int c = nt*16 + ln;
    bias_r[nt] = bias[c];
    sgn[nt] = (gnw[c]*scale[c] >= 0.f) ? 1.f : -1.f;
  }
  float s[4]  = {0.f,0.f,0.f,0.f};
  float sq[4] = {0.f,0.f,0.f,0.f};
  _Float16* wext = (_Float16*)ws;

  #pragma unroll 2
  for (int i = 0; i < 16; ++i) {
    const int wyl = wave*2 + (i >> 3), wxl = i & 7;
    const int base = (wyl*4*34 + wxl*4)*8;
    f32x4 acc[4];
    #pragma unroll
    for (int nt = 0; nt < 4; ++nt) {
      const float bv = bias_r[nt];
      acc[nt] = (f32x4){bv, bv, bv, bv};
    }
    #pragma unroll
    for (int c = 0; c < 3; ++c) {
      const f16x8 a = *(const f16x8*)&xs[base + aoff[c]];
      #pragma unroll
      for (int nt = 0; nt < 4; ++nt)
        acc[nt] = __builtin_amdgcn_mfma_f32_16x16x32_f16(a, bf[nt][c], acc[nt], 0, 0, 0);
    }
    const int wyg = ty*8 + wyl, wxg = tx*8 + wxl;
    if ((wyg < PWN) && (wxg < PWN)) {
      const size_t rowbase = ((size_t)(b*PWN + wyg)*PWN + wxg)*COUT;
      float m4[4];
      #pragma unroll
      for (int nt = 0; nt < 4; ++nt) {
        const float v0 = acc[nt][0], v1 = acc[nt][1];
        const float v2 = acc[nt][2], v3 = acc[nt][3];
        s[nt]  += (v0+v1) + (v2+v3);
        sq[nt] += v0*v0 + v1*v1 + v2*v2 + v3*v3;
        const float sg = sgn[nt];
        float m = fmaxf(fmaxf(sg*v0, sg*v1), fmaxf(sg*v2, sg*v3));
        m = fmaxf(m, __shfl_xor(m, 16, 64));
        m = fmaxf(m, __shfl_xor(m, 32, 64));
        m4[nt] = sg*m;
      }
      float mv = m4[0];
      mv = (q == 1) ? m4[1] : mv;
      mv = (q == 2) ? m4[2] : mv;
      mv = (q == 3) ? m4[3] : mv;
      wext[rowbase + lane] = (_Float16)mv;
    } else {
      const bool yv = (wyg*4 + q) < OH;
      #pragma unroll
      for (int nt = 0; nt < 4; ++nt) {
        #pragma unroll
        for (int r = 0; r < 4; ++r) {
          const bool okp = yv && (wxg*4 + r < OW);
          const float v = okp ? acc[nt][r] : 0.f;
          s[nt] += v; sq[nt] += v*v;
        }
      }
    }
  }
  #pragma unroll
  for (int nt = 0; nt < 4; ++nt) {
    float a = s[nt], c2 = sq[nt];
    a  += __shfl_xor(a, 16, 64);  a  += __shfl_xor(a, 32, 64);
    a  += __shfl_xor(a, 1, 64);   a  += __shfl_xor(a, 2, 64);
    c2 += __shfl_xor(c2, 16, 64); c2 += __shfl_xor(c2, 32, 64);
    c2 += __shfl_xor(c2, 1, 64);  c2 += __shfl_xor(c2, 2, 64);
    if (lane < 16 && (lane & 3) == 0) {
      red[wave][nt*4 + (ln >> 2)][0] = a;
      red[wave][nt*4 + (ln >> 2)][1] = c2;
    }
  }
  __syncthreads();
  if (tid < 32) {
    const int g = tid >> 1, k = tid & 1;
    const float t = red[0][g][k] + red[1][g][k] + red[2][g][k] + red[3][g][k];
    ws[OFF_PART_OLD + (((size_t)b*NGROUPS + g)*16 + tileIdx)*2 + k] = t;
  }
}

// ============================================================
// Fused tail, R12 restructure: both rows gathered up front (2x MLP),
// one vout[2][] transpose buffer, ONE barrier before a combined
// store sweep. 6 syncthreads/block -> 3.
// ============================================================
__global__ __launch_bounds__(256)
void tail_kernel(const float* __restrict__ gnw,
                 const float* __restrict__ gnb,
                 const float* __restrict__ scale,
                 const _Float16* __restrict__ wext,
                 const float* __restrict__ parts,
                 const int nparts,
                 float* __restrict__ out)
{
  __shared__ float stat[NGROUPS*2];
  __shared__ float AB[128];
  __shared__ float vout[2][COUT*PWN];   // [row][c*31+wx], 15.9KB

  const int tid = threadIdx.x;
  const int xb  = blockIdx.x;   // 0..15 -> rows 2*xb, 2*xb+1 (xb==15: 1 row)
  const int b   = blockIdx.y;

  if (tid < 32) {
    const int g = tid >> 1, k = tid & 1;
    const float* p = parts + ((size_t)(b*NGROUPS + g)*nparts)*2 + k;
    float a = 0.f;
    for (int t = 0; t < nparts; ++t) a += p[t*2];
    stat[g*2 + k] = a;
  }
  __syncthreads();
  if (tid < COUT) {
    const int c = tid, g = c >> 2;
    const float N = (float)(CPG * OH * OW);
    const float mean = stat[g*2] / N;
    const float var  = stat[g*2 + 1] / N - mean*mean;
    const float inv  = rsqrtf(var + 1e-5f);
    const float ag   = inv * gnw[c];
    AB[c]      = ag * scale[c];
    AB[64 + c] = (gnb[c] - mean * ag) * scale[c];
  }
  __syncthreads();

  const int wy0  = xb*2;
  const int nrow = (wy0 + 1 < PWN) ? 2 : 1;

  // gather + affine + clamp for both rows, transpose into vout
  if (tid < 248) {                        // 248*8 = 1984 ext elems per row
    const int wx = tid >> 3, c0 = (tid & 7)*8;
    for (int r = 0; r < nrow; ++r) {
      const size_t rb = (size_t)(b*PWN + wy0 + r)*PWN*COUT;
      const f16x8 e = *(const f16x8*)&wext[rb + tid*8];
      #pragma unroll
      for (int j = 0; j < 8; ++j) {
        const int c = c0 + j;
        float v = fmaf(AB[c], (float)e[j], AB[64 + c]);
        v = fminf(fmaxf(v, 0.f), 1.f);
        vout[r][c*PWN + wx] = v;
      }
    }
  }
  __syncthreads();

  // combined coalesced store sweep over both rows
  const int total = nrow*COUT*PWN;
  for (int e = tid; e < total; e += 256) {
    const int r = e / (COUT*PWN);
    const int o = e - r*(COUT*PWN);
    const int c = o / PWN, wx = o - c*PWN;
    out[(((size_t)b*COUT + c)*PWN + (wy0 + r))*PWN + wx] = vout[r][o];
  }
}

extern "C" void kernel_launch(void* const* d_in, const int* in_sizes, int n_in,
                              void* d_out, int out_size, void* d_ws, size_t ws_size,
                              hipStream_t stream)
{
  const float* x     = (const float*)d_in[0];
  const float* cw    = (const float*)d_in[1];
  const float* cb    = (const float*)d_in[2];
  const float* gnw   = (const float*)d_in[3];
  const float* gnb   = (const float*)d_in[4];
  const float* scale = (const float*)d_in[5];
  float* out = (float*)d_out;
  float* ws  = (float*)d_ws;

  if (ws_size >= WS_NEEDED) {
    _Float16* xh   = (_Float16*)ws;
    _Float16* wext = (_Float16*)((char*)ws + XH_BYTES);
    float*    prt  = (float*)((char*)ws + XH_BYTES + WEXT_BYTES);
    _Float16* wh   = (_Float16*)((char*)ws + XH_BYTES + WEXT_BYTES + PART_BYTES);

    xpack_kernel<<<dim3(XH_DIM + 1, NB), 192, 0, stream>>>(x, cw, xh, wh);
    conv_dma_kernel<<<dim3(4, NB), 512, 0, stream>>>(xh, wh, cb, gnw, scale, wext, prt);
    tail_kernel<<<dim3(16, NB), 256, 0, stream>>>(gnw, gnb, scale, wext, prt, 4, out);
  } else {
    conv_mfma_kernel<<<dim3(16, NB), 256, 0, stream>>>(x, cw, cb, gnw, scale, ws);
    tail_kernel<<<dim3(16, NB), 256, 0, stream>>>(gnw, gnb, scale,
                                                  (const _Float16*)ws,
                                                  ws + OFF_PART_OLD, 16, out);
  }
}

// Round 13
// 162.686 us; speedup vs baseline: 2.0861x; 1.0069x over previous
//
#include <hip/hip_runtime.h>
#include <math.h>

typedef _Float16 f16x8 __attribute__((ext_vector_type(8)));
typedef float f32x4 __attribute__((ext_vector_type(4)));

#define CIN 8
#define HIN 128
#define WIN 128
#define OH 126
#define OW 126
#define COUT 64
#define NB 128
#define NGROUPS 16
#define CPG 4
#define PWN 31
#define XROWS 34
#define XH_DIM 130            // padded image (2 halo rows/cols of zeros)
#define TPIX (34*34)          // 1156 pixels per tile
#define XSPAD 3072            // pads LDS to 54.4KB -> 2 blocks/CU -> VGPR budget 128

// ---- ws layout (bytes) ----
// xh f16 [b][iy][ix][ci] | wext f16 [b][wy][wx][c] | parts f32 | wh f16 [khw][n][ci]
#define XH_BYTES   ((size_t)NB*XH_DIM*XH_DIM*CIN*2)          // 34,611,200
#define WEXT_BYTES ((size_t)NB*PWN*PWN*COUT*2)               // 15,745,024
#define PART_BYTES ((size_t)NB*NGROUPS*4*2*4)                //     65,536
#define WH_BYTES   ((size_t)9*64*8*2)                        //      9,216
#define WS_NEEDED  (XH_BYTES + WEXT_BYTES + PART_BYTES + WH_BYTES)

// ---- old (fallback) ws layout ----
#define NPOOL (NB*PWN*PWN*COUT)
#define OFF_PART_OLD (NPOOL/2)   // f32 offset

// ============================================================
// R13 = R12 (measured 163.8us) with ONE change: tail 2 rows/block
// -> 4 rows/block (grid 16->8 per batch). R12 confirmed the tail is
// phase-latency-bound (BW floor ~4.5us, runs ~20us; all blocks
// co-resident so duration ~= one block's serialized phase chain).
// 4 rows amortizes the stat-load+AB latency phases 2x more and gives
// the gather 4-row MLP. vout[4][1984]=31.7KB -> 4 blocks/CU, 1024
// blocks all co-resident. conv/xpack BYTE-IDENTICAL to the
// twice-confirmed R5/R11/R12 source (codegen sensitivity lesson).
// Null (+-1.5us) => remaining tail is BW phase => declare plateau.
// ============================================================

// Pre-pack: x f32 NCHW -> xh f16 [b][iy][ix][ci] with zero halo;
// block XH_DIM additionally packs weights -> wh[khw][n][ci] f16.
__global__ __launch_bounds__(192)
void xpack_kernel(const float* __restrict__ x, const float* __restrict__ w,
                  _Float16* __restrict__ xh, _Float16* __restrict__ wh)
{
  const int iy = blockIdx.x;      // 0..129, 130 = weight block
  const int b  = blockIdx.y;
  if (iy == XH_DIM) {
    if (b != 0) return;
    for (int i = threadIdx.x; i < 9*64*8; i += 192) {
      const int khw = i >> 9, rem = i & 511;      // rem = n*8+ci
      wh[i] = (_Float16)w[rem*9 + khw];
    }
    return;
  }
  const int ix = threadIdx.x;     // active < 130
  if (ix >= XH_DIM) return;
  f16x8 pk = {0,0,0,0,0,0,0,0};
  if (iy < HIN && ix < WIN) {
    const float* xb = x + (size_t)b*CIN*HIN*WIN + iy*WIN + ix;
    #pragma unroll
    for (int ci = 0; ci < 8; ++ci)
      pk[ci] = (_Float16)xb[ci*HIN*WIN];
  }
  *(f16x8*)&xh[(((size_t)b*XH_DIM + iy)*XH_DIM + ix)*CIN] = pk;
}

// ============================================================
// Pipelined conv, strip-mapped (R3-verified lane map, in-lane
// pooling) inside the R4 DMA double-buffer structure.
//  - B fragments load from global wh (L2-hot), wls LDS deleted.
//  - strip mapping: pooling max is IN-LANE; no ds_bpermute per
//    window; store via tiny sbuf bounce.
//  - LDS padded to 54.4KB: 2 blocks/CU.
// BYTE-IDENTICAL to R11/R12 (measured-best). Do not perturb.
// ============================================================
__global__ __launch_bounds__(512)
void conv_dma_kernel(const _Float16* __restrict__ xh,
                     const _Float16* __restrict__ wh,
                     const float* __restrict__ bias,
                     const float* __restrict__ gnw,
                     const float* __restrict__ scale,
                     _Float16* __restrict__ wext,
                     float* __restrict__ parts)
{
  __shared__ __align__(16) _Float16 xs[2][TPIX*8 + XSPAD]; // 2 x 24,640 B
  __shared__ __align__(8)  _Float16 sbuf[8][256];          //   4,096 B
  __shared__ float red[8][16][2];                          //   1,024 B

  const int tid  = threadIdx.x;
  const int lane = tid & 63, wv = tid >> 6;     // 8 waves
  const int tx = blockIdx.x;                    // 0..3 (tile column)
  const int b  = blockIdx.y;
  const int ox0 = tx*32;

  const int q = lane >> 4, ln = lane & 15;

  // DMA one tile into xs[buf]: one f16x8 pixel per lane per instr.
  auto stage = [&](int buf, int ty) {
    const int oy0 = ty*32;
    #pragma unroll
    for (int k = 0; k < 3; ++k) {
      const int p = k*512 + tid;
      if (p < TPIX) {
        const int r = p / 34, c = p - r*34;
        const size_t gb = (((size_t)b*XH_DIM + (oy0 + r))*XH_DIM + (ox0 + c))*CIN;
        __builtin_amdgcn_global_load_lds(
            (const __attribute__((address_space(1))) void*)(xh + gb),
            (__attribute__((address_space(3))) void*)&xs[buf][p*8],
            16, 0, 0);
      }
    }
  };

  stage(0, 0);

  // B fragments straight from global (L2-hot, 9KB total, broadcast).
  f16x8 bf[4][3];
  #pragma unroll
  for (int nt = 0; nt < 4; ++nt) {
    #pragma unroll
    for (int c = 0; c < 2; ++c)
      bf[nt][c] = *(const f16x8*)&wh[((c*4 + q)*64 + nt*16 + ln)*8];
    if (q == 0)
      bf[nt][2] = *(const f16x8*)&wh[((8)*64 + nt*16 + ln)*8];
    else
      bf[nt][2] = (f16x8){0,0,0,0,0,0,0,0};
  }

  // strip A offsets: lane ln = x-offset m, quad q picks khw = c*4+q.
  int aoff[3];
  #pragma unroll
  for (int c = 0; c < 3; ++c) {
    const int khw = c*4 + q;               // 0..11
    const int ky = khw / 3, kx = khw - 3*(khw/3);
    aoff[c] = (khw < 9) ? (ky*34 + kx + ln)*8 : ln*8;  // padded taps -> B=0
  }

  float bias_r[4], sgn[4];
  #pragma unroll
  for (int nt = 0; nt < 4; ++nt) {
    const int c = nt*16 + ln;
    bias_r[nt] = bias[c];
    sgn[nt] = (gnw[c]*scale[c] >= 0.f) ? 1.f : -1.f;  // GN slope sign (inv>0)
  }

  float s[4]  = {0.f,0.f,0.f,0.f};
  float sq[4] = {0.f,0.f,0.f,0.f};

  // stats x-mask: strip positions 14,15 (q==3, regs 2,3) are conv-x
  // 126,127 when tx==3 && bd==1 -> excluded.
  const float xm_hi = (q < 3) ? 1.f : 0.f;

  asm volatile("s_waitcnt vmcnt(0)" ::: "memory");
  __syncthreads();

  for (int ty = 0; ty < 4; ++ty) {
    const int cur = ty & 1;
    if (ty < 3) stage(cur ^ 1, ty + 1);    // async prefetch next tile

    const int wy_g = ty*8 + wv;
    const int oy0  = ty*32;

    // 2 bands per wave (x0 = 0, 16); band = 4 strips = 4 pool windows
    #pragma unroll
    for (int bd = 0; bd < 2; ++bd) {
      const int x0 = bd << 4;
      const bool xedge = (tx == 3) && (bd == 1);

      float mx[4] = {-1e30f, -1e30f, -1e30f, -1e30f};

      #pragma unroll
      for (int sy = 0; sy < 4; ++sy) {
        const int y_l = wv*4 + sy;
        if (oy0 + y_l >= OH) break;        // uniform: only ty==3, wv==7, sy>=2
        const int base = (y_l*34 + x0)*8;

        f32x4 acc[4];
        #pragma unroll
        for (int nt = 0; nt < 4; ++nt) {
          const float bv = bias_r[nt];
          acc[nt] = (f32x4){bv, bv, bv, bv};  // bias as MFMA C operand
        }
        #pragma unroll
        for (int c = 0; c < 3; ++c) {
          const f16x8 a = *(const f16x8*)&xs[cur][base + aoff[c]];
          #pragma unroll
          for (int nt = 0; nt < 4; ++nt)
            acc[nt] = __builtin_amdgcn_mfma_f32_16x16x32_f16(a, bf[nt][c], acc[nt], 0, 0, 0);
        }

        // fully in-lane: stats + running window max (sign-domain)
        #pragma unroll
        for (int nt = 0; nt < 4; ++nt) {
          float v0 = acc[nt][0], v1 = acc[nt][1];
          float v2 = acc[nt][2], v3 = acc[nt][3];
          if (xedge) { v2 *= xm_hi; v3 *= xm_hi; }   // mask conv-x 126,127
          s[nt]  += (v0+v1) + (v2+v3);
          sq[nt] += v0*v0 + v1*v1 + v2*v2 + v3*v3;
          const float sg = sgn[nt];
          const float m = fmaxf(fmaxf(sg*v0, sg*v1), fmaxf(sg*v2, sg*v3));
          mx[nt] = fmaxf(mx[nt], m);
        }
      }

      // store band's 4 pooled windows: sbuf bounce -> coalesced store
      if (wy_g < PWN) {
        #pragma unroll
        for (int nt = 0; nt < 4; ++nt)
          sbuf[wv][q*64 + nt*16 + ln] = (_Float16)(sgn[nt]*mx[nt]);
        const int nw = xedge ? 3 : 4;      // window wx_g==31 dropped
        if (lane < nw*16) {
          const int wx0_g = tx*8 + (x0 >> 2);
          const uint2 v = *(const uint2*)&sbuf[wv][lane*4];
          *(uint2*)&wext[(((size_t)b*PWN + wy_g)*PWN + wx0_g)*COUT + lane*4] = v;
        }
      }
    }

    if (ty < 3) {
      asm volatile("s_waitcnt vmcnt(0)" ::: "memory");  // next tile DMA done
      __syncthreads();                                   // visible to all waves
    }
  }

  // per-wave stat reduce: quads (xor 16,32) then channels-in-group (xor 1,2)
  #pragma unroll
  for (int nt = 0; nt < 4; ++nt) {
    float a = s[nt], c2 = sq[nt];
    a  += __shfl_xor(a, 16, 64);  a  += __shfl_xor(a, 32, 64);
    a  += __shfl_xor(a, 1, 64);   a  += __shfl_xor(a, 2, 64);
    c2 += __shfl_xor(c2, 16, 64); c2 += __shfl_xor(c2, 32, 64);
    c2 += __shfl_xor(c2, 1, 64);  c2 += __shfl_xor(c2, 2, 64);
    if (lane < 16 && (lane & 3) == 0) {
      red[wv][nt*4 + (ln >> 2)][0] = a;
      red[wv][nt*4 + (ln >> 2)][1] = c2;
    }
  }
  __syncthreads();
  if (tid < 32) {
    const int g = tid >> 1, k = tid & 1;
    float t = 0.f;
    #pragma unroll
    for (int w8 = 0; w8 < 8; ++w8) t += red[w8][g][k];
    parts[(((size_t)b*NGROUPS + g)*4 + tx)*2 + k] = t;
  }
}

// ============================================================
// Fallback conv (proven R0/R2 path, old ws layout).
// ============================================================
__global__ __launch_bounds__(256)
void conv_mfma_kernel(const float* __restrict__ x,
                      const float* __restrict__ w,
                      const float* __restrict__ bias,
                      const float* __restrict__ gnw,
                      const float* __restrict__ scale,
                      float* __restrict__ ws)
{
  __shared__ __align__(16) _Float16 xs[XROWS*34*8];
  __shared__ __align__(16) _Float16 wls[9*64*8];
  __shared__ float red[4][16][2];

  const int tid  = threadIdx.x;
  const int lane = tid & 63, wave = tid >> 6;
  const int tileIdx = blockIdx.x;
  const int tx = tileIdx & 3, ty = tileIdx >> 2;
  const int b  = blockIdx.y;
  const int ox0 = tx*32, oy0 = ty*32;

  for (int idx = tid; idx < 9*64*8; idx += 256) {
    const int ci = idx & 7, n = (idx >> 3) & 63, khw = idx >> 9;
    wls[idx] = (_Float16)w[(n*CIN + ci)*9 + khw];
  }
  const float* xb = x + (size_t)b * CIN*HIN*WIN;
  for (int p = tid; p < XROWS*34; p += 256) {
    const int r = p / 34, c = p - r*34;
    const int iy = oy0 + r, ix = ox0 + c;
    const bool ok = (iy < HIN) && (ix < WIN);
    const int gbase = iy*WIN + ix;
    f16x8 pk;
    #pragma unroll
    for (int ci = 0; ci < 8; ++ci) {
      const float v = ok ? xb[ci*HIN*WIN + gbase] : 0.f;
      pk[ci] = (_Float16)v;
    }
    *(f16x8*)&xs[p*8] = pk;
  }
  __syncthreads();

  const int q = lane >> 4, ln = lane & 15;
  f16x8 bf[4][3];
  #pragma unroll
  for (int nt = 0; nt < 4; ++nt) {
    #pragma unroll
    for (int c = 0; c < 2; ++c)
      bf[nt][c] = *(const f16x8*)&wls[((c*4 + q)*64 + nt*16 + ln)*8];
    if (q == 0) bf[nt][2] = *(const f16x8*)&wls[((8)*64 + nt*16 + ln)*8];
    else        bf[nt][2] = (f16x8){0,0,0,0,0,0,0,0};
  }
  const int dy = ln >> 2, dx = ln & 3;
  int aoff[3];
  #pragma unroll
  for (int c = 0; c < 3; ++c) {
    const int khw = c*4 + q;
    const int ky = khw / 3, kx = khw - 3*(khw/3);
    aoff[c] = (khw < 9) ? ((dy + ky)*34 + (dx + kx))*8 : 0;
  }
  float bias_r[4], sgn[4];
  #pragma unroll
  for (int nt = 0; nt < 4; ++nt) {
    const int c = nt*16 + ln;
    bias_r[nt] = bias[c];
    sgn[nt] = (gnw[c]*scale[c] >= 0.f) ? 1.f : -1.f;
  }
  float s[4]  = {0.f,0.f,0.f,0.f};
  float sq[4] = {0.f,0.f,0.f,0.f};
  _Float16* wext = (_Float16*)ws;

  #pragma unroll 2
  for (int i = 0; i < 16; ++i) {
    const int wyl = wave*2 + (i >> 3), wxl = i & 7;
    const int base = (wyl*4*34 + wxl*4)*8;
    f32x4 acc[4];
    #pragma unroll
    for (int nt = 0; nt < 4; ++nt) {
      const float bv = bias_r[nt];
      acc[nt] = (f32x4){bv, bv, bv, bv};
    }
    #pragma unroll
    for (int c = 0; c < 3; ++c) {
      const f16x8 a = *(const f16x8*)&xs[base + aoff[c]];
      #pragma unroll
      for (int nt = 0; nt < 4; ++nt)
        acc[nt] = __builtin_amdgcn_mfma_f32_16x16x32_f16(a, bf[nt][c], acc[nt], 0, 0, 0);
    }
    const int wyg = ty*8 + wyl, wxg = tx*8 + wxl;
    if ((wyg < PWN) && (wxg < PWN)) {
      const size_t rowbase = ((size_t)(b*PWN + wyg)*PWN + wxg)*COUT;
      float m4[4];
      #pragma unroll
      for (int nt = 0; nt < 4; ++nt) {
        const float v0 = acc[nt][0], v1 = acc[nt][1];
        const float v2 = acc[nt][2], v3 = acc[nt][3];
        s[nt]  += (v0+v1) + (v2+v3);
        sq[nt] += v0*v0 + v1*v1 + v2*v2 + v3*v3;
        const float sg = sgn[nt];
        float m = fmaxf(fmaxf(sg*v0, sg*v1), fmaxf(sg*v2, sg*v3));
        m = fmaxf(m, __shfl_xor(m, 16, 64));
        m = fmaxf(m, __shfl_xor(m, 32, 64));
        m4[nt] = sg*m;
      }
      float mv = m4[0];
      mv = (q == 1) ? m4[1] : mv;
      mv = (q == 2) ? m4[2] : mv;
      mv = (q == 3) ? m4[3] : mv;
      wext[rowbase + lane] = (_Float16)mv;
    } else {
      const bool yv = (wyg*4 + q) < OH;
      #pragma unroll
      for (int nt = 0; nt < 4; ++nt) {
        #pragma unroll
        for (int r = 0; r < 4; ++r) {
          const bool okp = yv && (wxg*4 + r < OW);
          const float v = okp ? acc[nt][r] : 0.f;
          s[nt] += v; sq[nt] += v*v;
        }
      }
    }
  }
  #pragma unroll
  for (int nt = 0; nt < 4; ++nt) {
    float a = s[nt], c2 = sq[nt];
    a  += __shfl_xor(a, 16, 64);  a  += __shfl_xor(a, 32, 64);
    a  += __shfl_xor(a, 1, 64);   a  += __shfl_xor(a, 2, 64);
    c2 += __shfl_xor(c2, 16, 64); c2 += __shfl_xor(c2, 32, 64);
    c2 += __shfl_xor(c2, 1, 64);  c2 += __shfl_xor(c2, 2, 64);
    if (lane < 16 && (lane & 3) == 0) {
      red[wave][nt*4 + (ln >> 2)][0] = a;
      red[wave][nt*4 + (ln >> 2)][1] = c2;
    }
  }
  __syncthreads();
  if (tid < 32) {
    const int g = tid >> 1, k = tid & 1;
    const float t = red[0][g][k] + red[1][g][k] + red[2][g][k] + red[3][g][k];
    ws[OFF_PART_OLD + (((size_t)b*NGROUPS + g)*16 + tileIdx)*2 + k] = t;
  }
}

// ============================================================
// Fused tail, R13: 4 rows per block (grid 8 x NB). Stat phase paid
// 8x/batch instead of 16x; 4-row gather MLP. vout[4][] = 31.7KB.
// ============================================================
__global__ __launch_bounds__(256)
void tail_kernel(const float* __restrict__ gnw,
                 const float* __restrict__ gnb,
                 const float* __restrict__ scale,
                 const _Float16* __restrict__ wext,
                 const float* __restrict__ parts,
                 const int nparts,
                 float* __restrict__ out)
{
  __shared__ float stat[NGROUPS*2];
  __shared__ float AB[128];
  __shared__ float vout[4][COUT*PWN];   // [row][c*31+wx], 31.7KB

  const int tid = threadIdx.x;
  const int xb  = blockIdx.x;   // 0..7 -> rows 4*xb .. 4*xb+3 (xb==7: 3 rows)
  const int b   = blockIdx.y;

  if (tid < 32) {
    const int g = tid >> 1, k = tid & 1;
    const float* p = parts + ((size_t)(b*NGROUPS + g)*nparts)*2 + k;
    float a = 0.f;
    for (int t = 0; t < nparts; ++t) a += p[t*2];
    stat[g*2 + k] = a;
  }
  __syncthreads();
  if (tid < COUT) {
    const int c = tid, g = c >> 2;
    const float N = (float)(CPG * OH * OW);
    const float mean = stat[g*2] / N;
    const float var  = stat[g*2 + 1] / N - mean*mean;
    const float inv  = rsqrtf(var + 1e-5f);
    const float ag   = inv * gnw[c];
    AB[c]      = ag * scale[c];
    AB[64 + c] = (gnb[c] - mean * ag) * scale[c];
  }
  __syncthreads();

  const int wy0  = xb*4;
  const int nrow = (PWN - wy0 < 4) ? (PWN - wy0) : 4;

  // gather + affine + clamp for all rows, transpose into vout
  if (tid < 248) {                        // 248*8 = 1984 ext elems per row
    const int wx = tid >> 3, c0 = (tid & 7)*8;
    for (int r = 0; r < nrow; ++r) {
      const size_t rb = (size_t)(b*PWN + wy0 + r)*PWN*COUT;
      const f16x8 e = *(const f16x8*)&wext[rb + tid*8];
      #pragma unroll
      for (int j = 0; j < 8; ++j) {
        const int c = c0 + j;
        float v = fmaf(AB[c], (float)e[j], AB[64 + c]);
        v = fminf(fmaxf(v, 0.f), 1.f);
        vout[r][c*PWN + wx] = v;
      }
    }
  }
  __syncthreads();

  // combined coalesced store sweep over all rows
  const int total = nrow*COUT*PWN;
  for (int e = tid; e < total; e += 256) {
    const int r = e / (COUT*PWN);
    const int o = e - r*(COUT*PWN);
    const int c = o / PWN, wx = o - c*PWN;
    out[(((size_t)b*COUT + c)*PWN + (wy0 + r))*PWN + wx] = vout[r][o];
  }
}

extern "C" void kernel_launch(void* const* d_in, const int* in_sizes, int n_in,
                              void* d_out, int out_size, void* d_ws, size_t ws_size,
                              hipStream_t stream)
{
  const float* x     = (const float*)d_in[0];
  const float* cw    = (const float*)d_in[1];
  const float* cb    = (const float*)d_in[2];
  const float* gnw   = (const float*)d_in[3];
  const float* gnb   = (const float*)d_in[4];
  const float* scale = (const float*)d_in[5];
  float* out = (float*)d_out;
  float* ws  = (float*)d_ws;

  if (ws_size >= WS_NEEDED) {
    _Float16* xh   = (_Float16*)ws;
    _Float16* wext = (_Float16*)((char*)ws + XH_BYTES);
    float*    prt  = (float*)((char*)ws + XH_BYTES + WEXT_BYTES);
    _Float16* wh   = (_Float16*)((char*)ws + XH_BYTES + WEXT_BYTES + PART_BYTES);

    xpack_kernel<<<dim3(XH_DIM + 1, NB), 192, 0, stream>>>(x, cw, xh, wh);
    conv_dma_kernel<<<dim3(4, NB), 512, 0, stream>>>(xh, wh, cb, gnw, scale, wext, prt);
    tail_kernel<<<dim3(8, NB), 256, 0, stream>>>(gnw, gnb, scale, wext, prt, 4, out);
  } else {
    conv_mfma_kernel<<<dim3(16, NB), 256, 0, stream>>>(x, cw, cb, gnw, scale, ws);
    tail_kernel<<<dim3(16, NB), 256, 0, stream>>>(gnw, gnb, scale,
                                                  (const _Float16*)ws,
                                                  ws + OFF_PART_OLD, 16, out);
  }
}